// Round 3
// baseline (10308.855 us; speedup 1.0000x reference)
//
#include <hip/hip_runtime.h>

typedef unsigned int u32;
typedef _Float16 f16x2 __attribute__((ext_vector_type(2)));

#define TP 600
#define TQ 60
#define BB 64
#define EMB 344
#define HH 256
#define H2 128
#define GG 512

// ---------- fast math helpers ----------
__device__ __forceinline__ float exp2_fast(float x){
#if __has_builtin(__builtin_amdgcn_exp2f)
    return __builtin_amdgcn_exp2f(x);
#else
    return exp2f(x);
#endif
}
__device__ __forceinline__ float rcp_fast(float x){
#if __has_builtin(__builtin_amdgcn_rcpf)
    return __builtin_amdgcn_rcpf(x);
#else
    return 1.0f / x;
#endif
}
__device__ __forceinline__ float sigm_fast(float x){
    return rcp_fast(1.f + exp2_fast(-1.44269504f * x));
}
__device__ __forceinline__ float tanh_fast(float x){
    return 1.f - 2.f * rcp_fast(1.f + exp2_fast(2.88539008f * x));
}
__device__ __forceinline__ float dot2x(u32 w, u32 h, float acc){
    f16x2 wv = __builtin_bit_cast(f16x2, w);
    f16x2 hv = __builtin_bit_cast(f16x2, h);
    acc = fmaf((float)wv.x, (float)hv.x, acc);
    acc = fmaf((float)wv.y, (float)hv.y, acc);
    return acc;
}
__device__ __forceinline__ u32 pack2(float a, float b){
    f16x2 v; v.x = (_Float16)a; v.y = (_Float16)b;
    return __builtin_bit_cast(u32, v);
}

// ---------- prep: transpose weights (fp32 WT4 layout) + fp16 packing ----------
__global__ void prep_kernel(const float* __restrict__ pre0_Wih, const float* __restrict__ pre0_Whh,
                            const float* __restrict__ pre1_Wih, const float* __restrict__ pre1_Whh,
                            const float* __restrict__ Wq, const float* __restrict__ Wp,
                            const float* __restrict__ Whm,
                            const float* __restrict__ Whhm,
                            float* __restrict__ WT0, float* __restrict__ WT1,
                            float* __restrict__ WTq, float* __restrict__ WTp,
                            float* __restrict__ WTz, const float* __restrict__ Wihm,
                            u32* __restrict__ P0hh, u32* __restrict__ P1hh,
                            u32* __restrict__ PMhh, u32* __restrict__ PMwh)
{
    int g = blockIdx.x * blockDim.x + threadIdx.x;
    int gs = gridDim.x * blockDim.x;
    for (int idx = g; idx < 512*344; idx += gs) {
        int j = idx / 344, k = idx - j*344;
        WT0[((k>>2)*512 + j)*4 + (k&3)] = pre0_Wih[idx];
    }
    for (int idx = g; idx < 512*256; idx += gs) {
        int j = idx >> 8, k = idx & 255;
        WT1[((k>>2)*512 + j)*4 + (k&3)] = pre1_Wih[idx];
    }
    for (int idx = g; idx < 256*256; idx += gs) {
        int j = idx >> 8, k = idx & 255;
        WTq[((k>>2)*256 + j)*4 + (k&3)] = Wq[idx];
        WTp[((k>>2)*256 + j)*4 + (k&3)] = Wp[idx];
    }
    for (int idx = g; idx < 512*256; idx += gs) {
        int j = idx >> 8, k = idx & 255;
        WTz[((k>>2)*512 + j)*4 + (k&3)] = Wihm[j*512 + k];
    }
    for (int idx = g; idx < 64*512; idx += gs) {
        int k2 = idx >> 9, j = idx & 511;
        P0hh[idx] = pack2(pre0_Whh[j*128 + 2*k2], pre0_Whh[j*128 + 2*k2 + 1]);
        P1hh[idx] = pack2(pre1_Whh[j*128 + 2*k2], pre1_Whh[j*128 + 2*k2 + 1]);
        PMhh[idx] = pack2(Whhm[j*128 + 2*k2], Whhm[j*128 + 2*k2 + 1]);
    }
    for (int idx = g; idx < 64*256; idx += gs) {
        int k2 = idx >> 8, j = idx & 255;
        PMwh[idx] = pack2(Whm[j*128 + 2*k2], Whm[j*128 + 2*k2 + 1]);
    }
}

// ---------- batched projection ----------
template<int K, int M>
__global__ __launch_bounds__(M)
void proj_kernel(const float* __restrict__ X0, const float* __restrict__ W0,
                 const float* __restrict__ b0, float* __restrict__ C0, int T0,
                 const float* __restrict__ X1, const float* __restrict__ W1,
                 const float* __restrict__ b1, float* __restrict__ C1)
{
    __shared__ float Xs[K*68];
    int t = blockIdx.x;
    const float* X; const float* W; const float* bias; float* C; int trow;
    if (t < T0) { X = X0; W = W0; bias = b0; C = C0; trow = t; }
    else        { X = X1; W = W1; bias = b1; C = C1; trow = t - T0; }
    int j = threadIdx.x;
    for (int b = 0; b < 64; ++b) {
        for (int k = j; k < K; k += M)
            Xs[k*68 + b] = X[(trow*64 + b)*K + k];
    }
    __syncthreads();
    float acc[64];
    float binit = bias ? bias[j] : 0.f;
    #pragma unroll
    for (int b = 0; b < 64; ++b) acc[b] = binit;
    const float4* W4 = (const float4*)W;
    for (int k4 = 0; k4 < K/4; ++k4) {
        float4 w4 = W4[k4*M + j];
        float wv[4] = {w4.x, w4.y, w4.z, w4.w};
        #pragma unroll
        for (int kk = 0; kk < 4; ++kk) {
            int k = 4*k4 + kk;
            #pragma unroll
            for (int b4 = 0; b4 < 16; ++b4) {
                float4 x4 = *((const float4*)&Xs[k*68 + 4*b4]);
                acc[4*b4+0] = fmaf(wv[kk], x4.x, acc[4*b4+0]);
                acc[4*b4+1] = fmaf(wv[kk], x4.y, acc[4*b4+1]);
                acc[4*b4+2] = fmaf(wv[kk], x4.z, acc[4*b4+2]);
                acc[4*b4+3] = fmaf(wv[kk], x4.w, acc[4*b4+3]);
            }
        }
    }
    for (int b = 0; b < 64; ++b)
        C[(trow*64 + b)*M + j] = acc[b];
}

// ---------- Yq precompute ----------
__global__ __launch_bounds__(512)
void yq_kernel(const float* __restrict__ Hq1, const float* __restrict__ Wihm,
               float* __restrict__ Yq)
{
    __shared__ float Xs[256*68];
    int tq = blockIdx.x;
    int j = threadIdx.x;
    for (int b = 0; b < 64; ++b) {
        for (int k = j; k < 256; k += 512)
            Xs[k*68 + b] = Hq1[(tq*64 + b)*256 + k];
    }
    __syncthreads();
    float acc[64];
    #pragma unroll
    for (int b = 0; b < 64; ++b) acc[b] = 0.f;
    const float4* W4 = (const float4*)(Wihm + j*512 + 256);
    for (int k4 = 0; k4 < 64; ++k4) {
        float4 w4 = W4[k4];
        float wv[4] = {w4.x, w4.y, w4.z, w4.w};
        #pragma unroll
        for (int kk = 0; kk < 4; ++kk) {
            int k = 4*k4 + kk;
            #pragma unroll
            for (int b4 = 0; b4 < 16; ++b4) {
                float4 x4 = *((const float4*)&Xs[k*68 + 4*b4]);
                acc[4*b4+0] = fmaf(wv[kk], x4.x, acc[4*b4+0]);
                acc[4*b4+1] = fmaf(wv[kk], x4.y, acc[4*b4+1]);
                acc[4*b4+2] = fmaf(wv[kk], x4.z, acc[4*b4+2]);
                acc[4*b4+3] = fmaf(wv[kk], x4.w, acc[4*b4+3]);
            }
        }
    }
    for (int b = 0; b < 64; ++b)
        Yq[(tq*64 + b)*512 + j] = acc[b];
}

// ---------- pre-BiLSTM recurrence (h discarded; c masked; h = tanh(c)) ----------
__global__ __launch_bounds__(384, 2)
void rec_pre_kernel(const float* __restrict__ Xp, const float* __restrict__ Xq,
                    const u32* __restrict__ Whh,
                    const float* __restrict__ mask_p, const float* __restrict__ mask_q,
                    float* __restrict__ Hp, float* __restrict__ Hq)
{
    int bid = blockIdx.x;
    int sub = bid & 127; int b = sub >> 1; int dir = sub & 1;
    const float* X; const float* mask; float* Hout; int T;
    if (bid < 128) { X = Xp; mask = mask_p; Hout = Hp; T = TP; }
    else           { X = Xq; mask = mask_q; Hout = Hq; T = TQ; }
    int j = threadIdx.x;
    __shared__ __align__(16) _Float16 h16[128];
    __shared__ float gates[384];                // gate nonlinearity pre-applied
    u32 w[64];
    #pragma unroll
    for (int q = 0; q < 64; ++q) w[q] = Whh[q*512 + j];
    if (j < 128) h16[j] = (_Float16)0.f;
    float c = 0.f;
    int ti0 = dir ? (T-1) : 0;
    float x_c = X[(ti0*64 + b)*512 + j];
    float m_c = mask[ti0*64 + b];
    int cls = j >> 7;                            // 0:i 1:f 2:g (wave-uniform)
    __syncthreads();
    const uint4* h4p = (const uint4*)h16;
    for (int s = 0; s < T; ++s) {
        int ti = dir ? (T-1-s) : s;
        int s1 = (s+1 < T) ? (s+1) : s;
        int tn = dir ? (T-1-s1) : s1;
        float x_n = X[(tn*64 + b)*512 + j];
        float m_n = mask[tn*64 + b];
        float a0 = x_c, a1 = 0.f, a2 = 0.f, a3 = 0.f;
        #pragma unroll
        for (int q4 = 0; q4 < 4; ++q4) {
            uint4 h0 = h4p[4*q4+0], h1 = h4p[4*q4+1], h2 = h4p[4*q4+2], h3 = h4p[4*q4+3];
            a0 = dot2x(w[16*q4+ 0], h0.x, a0); a0 = dot2x(w[16*q4+ 1], h0.y, a0);
            a0 = dot2x(w[16*q4+ 2], h0.z, a0); a0 = dot2x(w[16*q4+ 3], h0.w, a0);
            a1 = dot2x(w[16*q4+ 4], h1.x, a1); a1 = dot2x(w[16*q4+ 5], h1.y, a1);
            a1 = dot2x(w[16*q4+ 6], h1.z, a1); a1 = dot2x(w[16*q4+ 7], h1.w, a1);
            a2 = dot2x(w[16*q4+ 8], h2.x, a2); a2 = dot2x(w[16*q4+ 9], h2.y, a2);
            a2 = dot2x(w[16*q4+10], h2.z, a2); a2 = dot2x(w[16*q4+11], h2.w, a2);
            a3 = dot2x(w[16*q4+12], h3.x, a3); a3 = dot2x(w[16*q4+13], h3.y, a3);
            a3 = dot2x(w[16*q4+14], h3.z, a3); a3 = dot2x(w[16*q4+15], h3.w, a3);
        }
        float g = (a0 + a1) + (a2 + a3);
        gates[j] = (cls == 2) ? tanh_fast(g) : sigm_fast(g);
        __syncthreads();
        if (j < 128) {
            float gi = gates[j], gf = gates[128+j], gg = gates[256+j];
            c = gf*c + gi*gg;
            c *= m_c;
            float h = tanh_fast(c);
            h16[j] = (_Float16)h;
            Hout[(ti*64 + b)*256 + dir*128 + j] = h;
        }
        __syncthreads();
        x_c = x_n; m_c = m_n;
    }
}

// ---------- Match-LSTM recurrence: one block per (b, dir) ----------
__global__ __launch_bounds__(512, 2)
void match_kernel(const float* __restrict__ ap,   // [600][64][256]
                  const float* __restrict__ aqg,  // [60][64][256]
                  const float* __restrict__ Zp,   // [600][64][512]
                  const float* __restrict__ Yq,   // [60][64][512]
                  const float* __restrict__ Wa,   // [256]
                  const float* __restrict__ mask_p,
                  const u32* __restrict__ PMwh,   // [64][256] packed Wh
                  const u32* __restrict__ PMhh,   // [64][512] packed Whh
                  float* __restrict__ out)        // [600][64][256]
{
    int bid = blockIdx.x; int b = bid >> 1; int dir = bid & 1;
    int tid = threadIdx.x;
    __shared__ __align__(16) u32 aq2[60*133];        // fp16 pairs of aq, odd stride
    __shared__ __align__(16) u32 Yq2_s[30*512];      // [tq-pair r][j]: pack2(Yq[2r][j],Yq[2r+1][j])
    __shared__ __align__(16) float sumt[256];
    __shared__ __align__(16) float wa_s[256];
    __shared__ __align__(16) float e_s[64];          // unnormalized softmax numerators (fp32!)
    __shared__ __align__(16) float Ssum_s[8];        // per-wave partial sums of e
    __shared__ __align__(16) _Float16 h16[128];
    __shared__ float gates[512];                     // gate nonlinearity pre-applied

    // ---- startup staging ----
    for (int idx = tid; idx < 60*128; idx += 512) {
        int tq = idx >> 7, h2 = idx & 127;
        float2 a = *(const float2*)&aqg[(tq*64 + b)*256 + 2*h2];
        aq2[tq*133 + h2] = pack2(a.x, a.y);
    }
    #pragma unroll 2
    for (int r = 0; r < 30; ++r) {
        float y0 = Yq[((2*r  )*64 + b)*512 + tid];
        float y1 = Yq[((2*r+1)*64 + b)*512 + tid];
        Yq2_s[r*512 + tid] = pack2(y0, y1);
    }
    if (tid < 256) wa_s[tid] = Wa[tid];
    if (tid < 128) h16[tid] = (_Float16)0.f;
    if (tid < 64) e_s[tid] = 0.f;

    u32 whh[64];
    #pragma unroll
    for (int q = 0; q < 64; ++q) whh[q] = PMhh[q*512 + tid];
    u32 wh[64];
    {
        int jw = tid & 255;
        #pragma unroll
        for (int q = 0; q < 64; ++q) wh[q] = PMwh[q*256 + jw];
    }
    float c = 0.f;
    int ti0 = dir ? (TP-1) : 0;
    float zp_c = Zp[(ti0*64 + b)*512 + tid];
    float ap_c = ap[(ti0*64 + b)*256 + (tid & 255)];
    float m_c  = mask_p[ti0*64 + b];
    int cls = tid >> 7;                               // gate class, wave-uniform
    __syncthreads();

    const uint4* h4p = (const uint4*)h16;

    for (int s = 0; s < TP; ++s) {
        int ti = dir ? (TP-1-s) : s;
        int s1 = (s+1 < TP) ? (s+1) : s;
        int tn = dir ? (TP-1-s1) : s1;

        // P1: sumt = ap_t + h @ Wh.T  (4 split accumulators)
        if (tid < 256) {
            float a0 = ap_c, a1 = 0.f, a2 = 0.f, a3 = 0.f;
            #pragma unroll
            for (int q4 = 0; q4 < 4; ++q4) {
                uint4 h0 = h4p[4*q4+0], h1 = h4p[4*q4+1], h2v = h4p[4*q4+2], h3 = h4p[4*q4+3];
                a0 = dot2x(wh[16*q4+ 0], h0.x, a0); a0 = dot2x(wh[16*q4+ 1], h0.y, a0);
                a0 = dot2x(wh[16*q4+ 2], h0.z, a0); a0 = dot2x(wh[16*q4+ 3], h0.w, a0);
                a1 = dot2x(wh[16*q4+ 4], h1.x, a1); a1 = dot2x(wh[16*q4+ 5], h1.y, a1);
                a1 = dot2x(wh[16*q4+ 6], h1.z, a1); a1 = dot2x(wh[16*q4+ 7], h1.w, a1);
                a2 = dot2x(wh[16*q4+ 8], h2v.x, a2); a2 = dot2x(wh[16*q4+ 9], h2v.y, a2);
                a2 = dot2x(wh[16*q4+10], h2v.z, a2); a2 = dot2x(wh[16*q4+11], h2v.w, a2);
                a3 = dot2x(wh[16*q4+12], h3.x, a3); a3 = dot2x(wh[16*q4+13], h3.y, a3);
                a3 = dot2x(wh[16*q4+14], h3.z, a3); a3 = dot2x(wh[16*q4+15], h3.w, a3);
            }
            sumt[tid] = (a0 + a1) + (a2 + a3);
        }
        __syncthreads();

        // prefetch next step's rows here: HBM latency covered by trans-heavy P2
        float zp_n = Zp[(tn*64 + b)*512 + tid];
        float ap_n = ap[(tn*64 + b)*256 + (tid & 255)];
        float m_n  = mask_p[tn*64 + b];

        // P2: scores -> e (no-max softmax; scores bounded), per-wave partial sums
        {
            int tq = tid >> 3, sb = tid & 7;
            float p0 = 0.f, p1 = 0.f, p2 = 0.f, p3 = 0.f;
            if (tq < 60) {
                #pragma unroll
                for (int i = 0; i < 16; i += 2) {
                    int h2a = sb + 8*i, h2b = sb + 8*(i+1);
                    f16x2 av = __builtin_bit_cast(f16x2, aq2[tq*133 + h2a]);
                    f16x2 bv = __builtin_bit_cast(f16x2, aq2[tq*133 + h2b]);
                    float2 sta = *(const float2*)&sumt[2*h2a];
                    float2 stb = *(const float2*)&sumt[2*h2b];
                    float2 wva = *(const float2*)&wa_s[2*h2a];
                    float2 wvb = *(const float2*)&wa_s[2*h2b];
                    p0 = fmaf(wva.x, tanh_fast((float)av.x + sta.x), p0);
                    p1 = fmaf(wva.y, tanh_fast((float)av.y + sta.y), p1);
                    p2 = fmaf(wvb.x, tanh_fast((float)bv.x + stb.x), p2);
                    p3 = fmaf(wvb.y, tanh_fast((float)bv.y + stb.y), p3);
                }
            }
            float part = (p0 + p2) + (p1 + p3);
            part += __shfl_xor(part, 1);
            part += __shfl_xor(part, 2);
            part += __shfl_xor(part, 4);
            float e = (tq < 60) ? exp2_fast(part * 1.44269504f) : 0.f;
            float s2 = e + __shfl_xor(e, 8);
            float s4 = s2 + __shfl_xor(s2, 16);
            float s8 = s4 + __shfl_xor(s4, 32);
            if (sb == 0 && tq < 60) e_s[tq] = e;
            if ((tid & 63) == 0) Ssum_s[tid >> 6] = s8;
        }
        __syncthreads();

        // P4: gates = Zp + rn*(sum_tq e_tq*Yq) + h@Whh.T ; nonlinearity applied in-place
        {
            float4 sA = *(const float4*)&Ssum_s[0];
            float4 sB = *(const float4*)&Ssum_s[4];
            float S = ((sA.x + sA.y) + (sA.z + sA.w)) + ((sB.x + sB.y) + (sB.z + sB.w));
            float rn = rcp_fast(S);
            float y0 = 0.f, y1 = 0.f;
            #pragma unroll
            for (int r = 0; r < 30; r += 2) {
                float2 e0 = *(const float2*)&e_s[2*r];
                float2 e1 = *(const float2*)&e_s[2*r+2];
                f16x2 ya = __builtin_bit_cast(f16x2, Yq2_s[r*512 + tid]);
                f16x2 yb = __builtin_bit_cast(f16x2, Yq2_s[(r+1)*512 + tid]);
                y0 = fmaf((float)ya.x, e0.x, y0);
                y1 = fmaf((float)ya.y, e0.y, y1);
                y0 = fmaf((float)yb.x, e1.x, y0);
                y1 = fmaf((float)yb.y, e1.y, y1);
            }
            float a0 = 0.f, a1 = 0.f, a2 = 0.f, a3 = 0.f;
            #pragma unroll
            for (int q4 = 0; q4 < 4; ++q4) {
                uint4 h0 = h4p[4*q4+0], h1 = h4p[4*q4+1], h2v = h4p[4*q4+2], h3 = h4p[4*q4+3];
                a0 = dot2x(whh[16*q4+ 0], h0.x, a0); a0 = dot2x(whh[16*q4+ 1], h0.y, a0);
                a0 = dot2x(whh[16*q4+ 2], h0.z, a0); a0 = dot2x(whh[16*q4+ 3], h0.w, a0);
                a1 = dot2x(whh[16*q4+ 4], h1.x, a1); a1 = dot2x(whh[16*q4+ 5], h1.y, a1);
                a1 = dot2x(whh[16*q4+ 6], h1.z, a1); a1 = dot2x(whh[16*q4+ 7], h1.w, a1);
                a2 = dot2x(whh[16*q4+ 8], h2v.x, a2); a2 = dot2x(whh[16*q4+ 9], h2v.y, a2);
                a2 = dot2x(whh[16*q4+10], h2v.z, a2); a2 = dot2x(whh[16*q4+11], h2v.w, a2);
                a3 = dot2x(whh[16*q4+12], h3.x, a3); a3 = dot2x(whh[16*q4+13], h3.y, a3);
                a3 = dot2x(whh[16*q4+14], h3.z, a3); a3 = dot2x(whh[16*q4+15], h3.w, a3);
            }
            float g = zp_c + rn * (y0 + y1) + ((a0 + a1) + (a2 + a3));
            gates[tid] = (cls == 2) ? tanh_fast(g) : sigm_fast(g);
        }
        __syncthreads();

        // P5: cell (nonlinearities already applied); h,c masked after cell
        if (tid < 128) {
            float gi = gates[tid], gf = gates[128+tid], gg = gates[256+tid], go = gates[384+tid];
            c = gf*c + gi*gg;
            float h = go * tanh_fast(c);
            h *= m_c; c *= m_c;
            h16[tid] = (_Float16)h;
            out[(ti*64 + b)*256 + dir*128 + tid] = h;
        }
        __syncthreads();
        zp_c = zp_n; ap_c = ap_n; m_c = m_n;
    }
}

// ---------- workspace layout (floats) ----------
#define O_BUFX   0UL          // 19,660,800  Xp0 -> Xp1 -> Zp
#define O_BUFXQ  19660800UL   //  1,966,080  Xq0 -> Xq1 -> Yq
#define O_HP0    21626880UL   //  9,830,400  Hp0 -> ap
#define O_HQ0    31457280UL   //    983,040  Hq0 -> aq
#define O_HP1    32440320UL   //  9,830,400
#define O_HQ1    42270720UL   //    983,040
#define O_WT0    43253760UL   //    176,128
#define O_WT1    43429888UL   //    131,072
#define O_WTQ    43560960UL   //     65,536
#define O_WTP    43626496UL   //     65,536
#define O_WTZ    43692032UL   //    131,072
#define O_P0HH   43823104UL   //     32,768 u32
#define O_P1HH   43855872UL
#define O_PMHH   43888640UL
#define O_PMWH   43921408UL   //     16,384 u32

extern "C" void kernel_launch(void* const* d_in, const int* in_sizes, int n_in,
                              void* d_out, int out_size, void* d_ws, size_t ws_size,
                              hipStream_t stream)
{
    const float* passage  = (const float*)d_in[0];
    const float* question = (const float*)d_in[1];
    const float* mask_p   = (const float*)d_in[2];
    const float* mask_q   = (const float*)d_in[3];
    const float* pre0_Wih = (const float*)d_in[4];
    const float* pre0_Whh = (const float*)d_in[5];
    const float* pre0_b   = (const float*)d_in[6];
    const float* pre1_Wih = (const float*)d_in[7];
    const float* pre1_Whh = (const float*)d_in[8];
    const float* pre1_b   = (const float*)d_in[9];
    const float* mq_Wq    = (const float*)d_in[10];
    const float* mq_Wp    = (const float*)d_in[11];
    const float* mq_bp    = (const float*)d_in[12];
    const float* mq_Wh    = (const float*)d_in[13];
    const float* mq_Wa    = (const float*)d_in[14];
    // d_in[15] = mq_ba: softmax-invariant, skipped
    const float* mq_Wih   = (const float*)d_in[16];
    const float* mq_Whh   = (const float*)d_in[17];
    const float* mq_b     = (const float*)d_in[18];

    float* ws = (float*)d_ws;
    float* bufX  = ws + O_BUFX;
    float* bufXq = ws + O_BUFXQ;
    float* Hp0   = ws + O_HP0;
    float* Hq0   = ws + O_HQ0;
    float* Hp1   = ws + O_HP1;
    float* Hq1   = ws + O_HQ1;
    float* WT0   = ws + O_WT0;
    float* WT1   = ws + O_WT1;
    float* WTq   = ws + O_WTQ;
    float* WTp   = ws + O_WTP;
    float* WTz   = ws + O_WTZ;
    u32*   P0hh  = (u32*)(ws + O_P0HH);
    u32*   P1hh  = (u32*)(ws + O_P1HH);
    u32*   PMhh  = (u32*)(ws + O_PMHH);
    u32*   PMwh  = (u32*)(ws + O_PMWH);
    float* ap = Hp0;   // Hp0 dead after proj1
    float* aq = Hq0;
    float* Zp = bufX;  // Xp1 dead after rec1
    float* Yq = bufXq; // Xq1 dead after rec1

    prep_kernel<<<688, 256, 0, stream>>>(pre0_Wih, pre0_Whh, pre1_Wih, pre1_Whh,
                                         mq_Wq, mq_Wp, mq_Wh, mq_Whh,
                                         WT0, WT1, WTq, WTp, WTz, mq_Wih,
                                         P0hh, P1hh, PMhh, PMwh);
    proj_kernel<EMB, 512><<<660, 512, 0, stream>>>(passage, WT0, pre0_b, bufX, TP,
                                                   question, WT0, pre0_b, bufXq);
    rec_pre_kernel<<<256, 384, 0, stream>>>(bufX, bufXq, P0hh, mask_p, mask_q, Hp0, Hq0);
    proj_kernel<256, 512><<<660, 512, 0, stream>>>(Hp0, WT1, pre1_b, bufX, TP,
                                                   Hq0, WT1, pre1_b, bufXq);
    rec_pre_kernel<<<256, 384, 0, stream>>>(bufX, bufXq, P1hh, mask_p, mask_q, Hp1, Hq1);
    proj_kernel<256, 256><<<660, 256, 0, stream>>>(Hp1, WTp, mq_bp, ap, TP,
                                                   Hq1, WTq, nullptr, aq);
    proj_kernel<256, 512><<<600, 512, 0, stream>>>(Hp1, WTz, mq_b, Zp, TP,
                                                   nullptr, nullptr, nullptr, nullptr);
    yq_kernel<<<60, 512, 0, stream>>>(Hq1, mq_Wih, Yq);
    match_kernel<<<128, 512, 0, stream>>>(ap, aq, Zp, Yq, mq_Wa, mask_p,
                                          PMwh, PMhh, (float*)d_out);
}

// Round 4
// 8473.450 us; speedup vs baseline: 1.2166x; 1.2166x over previous
//
#include <hip/hip_runtime.h>

typedef unsigned int u32;
typedef _Float16 f16x2 __attribute__((ext_vector_type(2)));

#define TP 600
#define TQ 60
#define BB 64
#define EMB 344
#define HH 256
#define H2 128
#define GG 512

// ---------- fast math helpers ----------
__device__ __forceinline__ float exp2_fast(float x){
#if __has_builtin(__builtin_amdgcn_exp2f)
    return __builtin_amdgcn_exp2f(x);
#else
    return exp2f(x);
#endif
}
__device__ __forceinline__ float rcp_fast(float x){
#if __has_builtin(__builtin_amdgcn_rcpf)
    return __builtin_amdgcn_rcpf(x);
#else
    return 1.0f / x;
#endif
}
__device__ __forceinline__ float sigm_fast(float x){
    return rcp_fast(1.f + exp2_fast(-1.44269504f * x));
}
__device__ __forceinline__ float tanh_fast(float x){
    return 1.f - 2.f * rcp_fast(1.f + exp2_fast(2.88539008f * x));
}
__device__ __forceinline__ float dot2x(u32 w, u32 h, float acc){
    f16x2 wv = __builtin_bit_cast(f16x2, w);
    f16x2 hv = __builtin_bit_cast(f16x2, h);
    acc = fmaf((float)wv.x, (float)hv.x, acc);
    acc = fmaf((float)wv.y, (float)hv.y, acc);
    return acc;
}
__device__ __forceinline__ u32 pack2(float a, float b){
    f16x2 v; v.x = (_Float16)a; v.y = (_Float16)b;
    return __builtin_bit_cast(u32, v);
}
// wave-wide broadcast of lane l's copy of v (VALU pipe, not LDS pipe)
__device__ __forceinline__ u32 lane_bcast(u32 v, int l){
    return (u32)__builtin_amdgcn_readlane((int)v, l);
}

// ---------- prep: transpose weights (fp32 WT4 layout) + fp16 packing ----------
__global__ void prep_kernel(const float* __restrict__ pre0_Wih, const float* __restrict__ pre0_Whh,
                            const float* __restrict__ pre1_Wih, const float* __restrict__ pre1_Whh,
                            const float* __restrict__ Wq, const float* __restrict__ Wp,
                            const float* __restrict__ Whm,
                            const float* __restrict__ Whhm,
                            float* __restrict__ WT0, float* __restrict__ WT1,
                            float* __restrict__ WTq, float* __restrict__ WTp,
                            float* __restrict__ WTz, const float* __restrict__ Wihm,
                            u32* __restrict__ P0hh, u32* __restrict__ P1hh,
                            u32* __restrict__ PMhh, u32* __restrict__ PMwh)
{
    int g = blockIdx.x * blockDim.x + threadIdx.x;
    int gs = gridDim.x * blockDim.x;
    for (int idx = g; idx < 512*344; idx += gs) {
        int j = idx / 344, k = idx - j*344;
        WT0[((k>>2)*512 + j)*4 + (k&3)] = pre0_Wih[idx];
    }
    for (int idx = g; idx < 512*256; idx += gs) {
        int j = idx >> 8, k = idx & 255;
        WT1[((k>>2)*512 + j)*4 + (k&3)] = pre1_Wih[idx];
    }
    for (int idx = g; idx < 256*256; idx += gs) {
        int j = idx >> 8, k = idx & 255;
        WTq[((k>>2)*256 + j)*4 + (k&3)] = Wq[idx];
        WTp[((k>>2)*256 + j)*4 + (k&3)] = Wp[idx];
    }
    for (int idx = g; idx < 512*256; idx += gs) {
        int j = idx >> 8, k = idx & 255;
        WTz[((k>>2)*512 + j)*4 + (k&3)] = Wihm[j*512 + k];
    }
    for (int idx = g; idx < 64*512; idx += gs) {
        int k2 = idx >> 9, j = idx & 511;
        P0hh[idx] = pack2(pre0_Whh[j*128 + 2*k2], pre0_Whh[j*128 + 2*k2 + 1]);
        P1hh[idx] = pack2(pre1_Whh[j*128 + 2*k2], pre1_Whh[j*128 + 2*k2 + 1]);
        PMhh[idx] = pack2(Whhm[j*128 + 2*k2], Whhm[j*128 + 2*k2 + 1]);
    }
    for (int idx = g; idx < 64*256; idx += gs) {
        int k2 = idx >> 8, j = idx & 255;
        PMwh[idx] = pack2(Whm[j*128 + 2*k2], Whm[j*128 + 2*k2 + 1]);
    }
}

// ---------- batched projection ----------
template<int K, int M>
__global__ __launch_bounds__(M)
void proj_kernel(const float* __restrict__ X0, const float* __restrict__ W0,
                 const float* __restrict__ b0, float* __restrict__ C0, int T0,
                 const float* __restrict__ X1, const float* __restrict__ W1,
                 const float* __restrict__ b1, float* __restrict__ C1)
{
    __shared__ float Xs[K*68];
    int t = blockIdx.x;
    const float* X; const float* W; const float* bias; float* C; int trow;
    if (t < T0) { X = X0; W = W0; bias = b0; C = C0; trow = t; }
    else        { X = X1; W = W1; bias = b1; C = C1; trow = t - T0; }
    int j = threadIdx.x;
    for (int b = 0; b < 64; ++b) {
        for (int k = j; k < K; k += M)
            Xs[k*68 + b] = X[(trow*64 + b)*K + k];
    }
    __syncthreads();
    float acc[64];
    float binit = bias ? bias[j] : 0.f;
    #pragma unroll
    for (int b = 0; b < 64; ++b) acc[b] = binit;
    const float4* W4 = (const float4*)W;
    for (int k4 = 0; k4 < K/4; ++k4) {
        float4 w4 = W4[k4*M + j];
        float wv[4] = {w4.x, w4.y, w4.z, w4.w};
        #pragma unroll
        for (int kk = 0; kk < 4; ++kk) {
            int k = 4*k4 + kk;
            #pragma unroll
            for (int b4 = 0; b4 < 16; ++b4) {
                float4 x4 = *((const float4*)&Xs[k*68 + 4*b4]);
                acc[4*b4+0] = fmaf(wv[kk], x4.x, acc[4*b4+0]);
                acc[4*b4+1] = fmaf(wv[kk], x4.y, acc[4*b4+1]);
                acc[4*b4+2] = fmaf(wv[kk], x4.z, acc[4*b4+2]);
                acc[4*b4+3] = fmaf(wv[kk], x4.w, acc[4*b4+3]);
            }
        }
    }
    for (int b = 0; b < 64; ++b)
        C[(trow*64 + b)*M + j] = acc[b];
}

// ---------- Yq precompute ----------
__global__ __launch_bounds__(512)
void yq_kernel(const float* __restrict__ Hq1, const float* __restrict__ Wihm,
               float* __restrict__ Yq)
{
    __shared__ float Xs[256*68];
    int tq = blockIdx.x;
    int j = threadIdx.x;
    for (int b = 0; b < 64; ++b) {
        for (int k = j; k < 256; k += 512)
            Xs[k*68 + b] = Hq1[(tq*64 + b)*256 + k];
    }
    __syncthreads();
    float acc[64];
    #pragma unroll
    for (int b = 0; b < 64; ++b) acc[b] = 0.f;
    const float4* W4 = (const float4*)(Wihm + j*512 + 256);
    for (int k4 = 0; k4 < 64; ++k4) {
        float4 w4 = W4[k4];
        float wv[4] = {w4.x, w4.y, w4.z, w4.w};
        #pragma unroll
        for (int kk = 0; kk < 4; ++kk) {
            int k = 4*k4 + kk;
            #pragma unroll
            for (int b4 = 0; b4 < 16; ++b4) {
                float4 x4 = *((const float4*)&Xs[k*68 + 4*b4]);
                acc[4*b4+0] = fmaf(wv[kk], x4.x, acc[4*b4+0]);
                acc[4*b4+1] = fmaf(wv[kk], x4.y, acc[4*b4+1]);
                acc[4*b4+2] = fmaf(wv[kk], x4.z, acc[4*b4+2]);
                acc[4*b4+3] = fmaf(wv[kk], x4.w, acc[4*b4+3]);
            }
        }
    }
    for (int b = 0; b < 64; ++b)
        Yq[(tq*64 + b)*512 + j] = acc[b];
}

// ---------- pre-BiLSTM recurrence (h discarded; c masked; h = tanh(c)) ----------
__global__ __launch_bounds__(384, 2)
void rec_pre_kernel(const float* __restrict__ Xp, const float* __restrict__ Xq,
                    const u32* __restrict__ Whh,
                    const float* __restrict__ mask_p, const float* __restrict__ mask_q,
                    float* __restrict__ Hp, float* __restrict__ Hq)
{
    int bid = blockIdx.x;
    int sub = bid & 127; int b = sub >> 1; int dir = sub & 1;
    const float* X; const float* mask; float* Hout; int T;
    if (bid < 128) { X = Xp; mask = mask_p; Hout = Hp; T = TP; }
    else           { X = Xq; mask = mask_q; Hout = Hq; T = TQ; }
    int j = threadIdx.x;
    __shared__ __align__(16) _Float16 h16[128];
    __shared__ float gates[384];
    u32 w[64];
    #pragma unroll
    for (int q = 0; q < 64; ++q) w[q] = Whh[q*512 + j];
    if (j < 128) h16[j] = (_Float16)0.f;
    float c = 0.f;
    int ti0 = dir ? (T-1) : 0;
    float x_c = X[(ti0*64 + b)*512 + j];
    float m_c = mask[ti0*64 + b];
    int cls = j >> 7;                            // 0:i 1:f 2:g (wave-uniform)
    __syncthreads();
    const u32* h32 = (const u32*)h16;
    for (int s = 0; s < T; ++s) {
        int ti = dir ? (T-1-s) : s;
        int s1 = (s+1 < T) ? (s+1) : s;
        int tn = dir ? (T-1-s1) : s1;
        float x_n = X[(tn*64 + b)*512 + j];
        float m_n = mask[tn*64 + b];
        // cooperative h read: lane l holds pair l; broadcast via readlane
        u32 hp = h32[j & 63];
        float a0 = x_c, a1 = 0.f, a2 = 0.f, a3 = 0.f;
        #pragma unroll
        for (int q = 0; q < 64; q += 4) {
            u32 h0 = lane_bcast(hp, q),   h1 = lane_bcast(hp, q+1);
            u32 h2v = lane_bcast(hp, q+2), h3 = lane_bcast(hp, q+3);
            a0 = dot2x(w[q],   h0,  a0);
            a1 = dot2x(w[q+1], h1,  a1);
            a2 = dot2x(w[q+2], h2v, a2);
            a3 = dot2x(w[q+3], h3,  a3);
        }
        float g = (a0 + a1) + (a2 + a3);
        gates[j] = (cls == 2) ? tanh_fast(g) : sigm_fast(g);
        __syncthreads();
        if (j < 128) {
            float gi = gates[j], gf = gates[128+j], gg = gates[256+j];
            c = gf*c + gi*gg;
            c *= m_c;
            float h = tanh_fast(c);
            h16[j] = (_Float16)h;
            Hout[(ti*64 + b)*256 + dir*128 + j] = h;
        }
        __syncthreads();
        x_c = x_n; m_c = m_n;
    }
}

// ---------- Match-LSTM recurrence: one block per (b, dir) ----------
__global__ __launch_bounds__(512, 2)
void match_kernel(const float* __restrict__ ap,   // [600][64][256]
                  const float* __restrict__ aqg,  // [60][64][256]
                  const float* __restrict__ Zp,   // [600][64][512]
                  const float* __restrict__ Yq,   // [60][64][512]
                  const float* __restrict__ Wa,   // [256]
                  const float* __restrict__ mask_p,
                  const u32* __restrict__ PMwh,   // [64][256] packed Wh
                  const u32* __restrict__ PMhh,   // [64][512] packed Whh
                  float* __restrict__ out)        // [600][64][256]
{
    int bid = blockIdx.x; int b = bid >> 1; int dir = bid & 1;
    int tid = threadIdx.x;
    __shared__ __align__(16) uint4 Yq4s[8*512];      // [r4][j]: pairs (4r4..4r4+3) of tq
    __shared__ __align__(16) u32 aq16[64*132];       // [tq][pair p], row stride 132
    __shared__ float gates[512];
    __shared__ __align__(16) u32 sumt16[160];        // [sb][20]: pairs [16sb..16sb+16)
    __shared__ __align__(16) _Float16 h16[128];
    __shared__ __align__(16) _Float16 e16[64];

    // ---- startup staging ----
    for (int idx = tid; idx < 60*128; idx += 512) {
        int tq = idx >> 7, p = idx & 127;
        float2 a = *(const float2*)&aqg[(tq*64 + b)*256 + 2*p];
        aq16[tq*132 + p] = pack2(a.x, a.y);
    }
    for (int idx = tid; idx < 4*132; idx += 512)     // zero pad rows 60..63
        aq16[60*132 + idx] = 0u;
    #pragma unroll
    for (int r4 = 0; r4 < 8; ++r4) {
        float v[8];
        #pragma unroll
        for (int k = 0; k < 8; ++k) {
            int tq = 8*r4 + k;
            v[k] = (tq < 60) ? Yq[(tq*64 + b)*512 + tid] : 0.f;
        }
        Yq4s[r4*512 + tid] = make_uint4(pack2(v[0],v[1]), pack2(v[2],v[3]),
                                        pack2(v[4],v[5]), pack2(v[6],v[7]));
    }
    if (tid < 128) h16[tid] = (_Float16)0.f;

    // per-lane wa slice registers (pairs [16sb..16sb+16))
    int sb = tid & 7;
    u32 wa_reg[16];
    #pragma unroll
    for (int i = 0; i < 16; ++i) {
        float2 w2 = *(const float2*)&Wa[32*sb + 2*i];
        wa_reg[i] = pack2(w2.x, w2.y);
    }
    u32 whh[64];
    #pragma unroll
    for (int q = 0; q < 64; ++q) whh[q] = PMhh[q*512 + tid];
    u32 wh[64];
    {
        int jw = tid & 255;
        #pragma unroll
        for (int q = 0; q < 64; ++q) wh[q] = PMwh[q*256 + jw];
    }
    float c = 0.f;
    int ti0 = dir ? (TP-1) : 0;
    float zp_c = Zp[(ti0*64 + b)*512 + tid];
    float ap_c = (tid < 256) ? ap[(ti0*64 + b)*256 + tid] : 0.f;
    float m_c  = mask_p[ti0*64 + b];
    int cls = tid >> 7;                               // gate class, wave-uniform
    const u32 ONE2 = 0x3C003C00u;                     // fp16 (1.0, 1.0)
    __syncthreads();

    const u32* h32 = (const u32*)h16;
    const u32* e32 = (const u32*)e16;

    for (int s = 0; s < TP; ++s) {
        int ti = dir ? (TP-1-s) : s;
        int s1 = (s+1 < TP) ? (s+1) : s;
        int tn = dir ? (TP-1-s1) : s1;

        // ---- P1: hWhh[tid] (kept in reg) and sumt = ap + h@Wh.T (tid<256) ----
        u32 hp = h32[tid & 63];                       // coop read: lane l holds pair l
        float w0 = 0.f, w1 = 0.f, w2a = 0.f, w3a = 0.f;
        if (tid < 256) {
            float s0 = ap_c, s1a = 0.f, s2 = 0.f, s3 = 0.f;
            #pragma unroll
            for (int q = 0; q < 64; q += 4) {
                u32 h0 = lane_bcast(hp, q),   h1 = lane_bcast(hp, q+1);
                u32 h2v = lane_bcast(hp, q+2), h3 = lane_bcast(hp, q+3);
                w0  = dot2x(whh[q],   h0,  w0);  s0  = dot2x(wh[q],   h0,  s0);
                w1  = dot2x(whh[q+1], h1,  w1);  s1a = dot2x(wh[q+1], h1,  s1a);
                w2a = dot2x(whh[q+2], h2v, w2a); s2  = dot2x(wh[q+2], h2v, s2);
                w3a = dot2x(whh[q+3], h3,  w3a); s3  = dot2x(wh[q+3], h3,  s3);
            }
            float st = (s0 + s1a) + (s2 + s3);
            float so = __shfl_xor(st, 1);
            if ((tid & 1) == 0) {
                int p = tid >> 1;
                sumt16[(p >> 4)*20 + (p & 15)] = pack2(st, so);
            }
        } else {
            #pragma unroll
            for (int q = 0; q < 64; q += 4) {
                u32 h0 = lane_bcast(hp, q),   h1 = lane_bcast(hp, q+1);
                u32 h2v = lane_bcast(hp, q+2), h3 = lane_bcast(hp, q+3);
                w0  = dot2x(whh[q],   h0,  w0);
                w1  = dot2x(whh[q+1], h1,  w1);
                w2a = dot2x(whh[q+2], h2v, w2a);
                w3a = dot2x(whh[q+3], h3,  w3a);
            }
        }
        float hwhh = (w0 + w1) + (w2a + w3a);
        __syncthreads();                              // bar1

        // prefetch next step rows (drained at bar2; covered by P2 transcendentals)
        float zp_n = Zp[(tn*64 + b)*512 + tid];
        float ap_n = (tid < 256) ? ap[(tn*64 + b)*256 + tid] : 0.f;
        float m_n  = mask_p[tn*64 + b];

        // ---- P2: scores -> e16 (clamped, fp16) ----
        {
            int tq = tid >> 3;
            const uint4* sv4 = (const uint4*)&sumt16[sb*20];
            const uint4* av4 = (const uint4*)&aq16[tq*132 + 16*sb];
            uint4 sv0 = sv4[0], sv1 = sv4[1], sv2 = sv4[2], sv3 = sv4[3];
            uint4 av0 = av4[0], av1 = av4[1], av2 = av4[2], av3 = av4[3];
            float p0 = 0.f, p1 = 0.f, p2 = 0.f, p3 = 0.f;
            u32 sa[16] = {sv0.x,sv0.y,sv0.z,sv0.w, sv1.x,sv1.y,sv1.z,sv1.w,
                          sv2.x,sv2.y,sv2.z,sv2.w, sv3.x,sv3.y,sv3.z,sv3.w};
            u32 aa[16] = {av0.x,av0.y,av0.z,av0.w, av1.x,av1.y,av1.z,av1.w,
                          av2.x,av2.y,av2.z,av2.w, av3.x,av3.y,av3.z,av3.w};
            #pragma unroll
            for (int i = 0; i < 16; i += 4) {
                #pragma unroll
                for (int k = 0; k < 4; ++k) {
                    f16x2 av = __builtin_bit_cast(f16x2, aa[i+k]);
                    f16x2 sv = __builtin_bit_cast(f16x2, sa[i+k]);
                    f16x2 wv = __builtin_bit_cast(f16x2, wa_reg[i+k]);
                    float& pa = (k & 1) ? p2 : p0;
                    float& pb = (k & 1) ? p3 : p1;
                    pa = fmaf((float)wv.x, tanh_fast((float)av.x + (float)sv.x), pa);
                    pb = fmaf((float)wv.y, tanh_fast((float)av.y + (float)sv.y), pb);
                }
            }
            float part = (p0 + p1) + (p2 + p3);
            part += __shfl_xor(part, 1);
            part += __shfl_xor(part, 2);
            part += __shfl_xor(part, 4);
            float sc = fminf(9.f, fmaxf(-9.f, part));
            float e = exp2_fast(sc * 1.44269504f);
            if (tq >= 60) e = 0.f;
            if (sb == 0) e16[tq] = (_Float16)e;
        }
        __syncthreads();                              // bar2

        // ---- P4: gates = Zp + rn*(sum_tq e*Yq) + hWhh ; nonlinearity fused ----
        {
            u32 ep = e32[tid & 31];                   // coop read: lane l holds e-pair l
            float y0 = 0.f, y1 = 0.f, S0 = 0.f, S1 = 0.f;
            #pragma unroll
            for (int r4 = 0; r4 < 8; ++r4) {
                uint4 yv = Yq4s[r4*512 + tid];
                u32 e0 = lane_bcast(ep, 4*r4+0), e1 = lane_bcast(ep, 4*r4+1);
                u32 e2 = lane_bcast(ep, 4*r4+2), e3 = lane_bcast(ep, 4*r4+3);
                y0 = dot2x(yv.x, e0, y0); S0 = dot2x(ONE2, e0, S0);
                y1 = dot2x(yv.y, e1, y1); S1 = dot2x(ONE2, e1, S1);
                y0 = dot2x(yv.z, e2, y0); S0 = dot2x(ONE2, e2, S0);
                y1 = dot2x(yv.w, e3, y1); S1 = dot2x(ONE2, e3, S1);
            }
            float rn = rcp_fast(S0 + S1);
            float g = zp_c + rn * (y0 + y1) + hwhh;
            gates[tid] = (cls == 2) ? tanh_fast(g) : sigm_fast(g);
        }
        __syncthreads();                              // bar3

        // ---- P5: cell; h,c masked after cell ----
        if (tid < 128) {
            float gi = gates[tid], gf = gates[128+tid], gg = gates[256+tid], go = gates[384+tid];
            c = gf*c + gi*gg;
            float h = go * tanh_fast(c);
            h *= m_c; c *= m_c;
            h16[tid] = (_Float16)h;
            out[(ti*64 + b)*256 + dir*128 + tid] = h;
        }
        __syncthreads();                              // bar4 (h ready)
        zp_c = zp_n; ap_c = ap_n; m_c = m_n;
    }
}

// ---------- workspace layout (floats) ----------
#define O_BUFX   0UL          // 19,660,800  Xp0 -> Xp1 -> Zp
#define O_BUFXQ  19660800UL   //  1,966,080  Xq0 -> Xq1 -> Yq
#define O_HP0    21626880UL   //  9,830,400  Hp0 -> ap
#define O_HQ0    31457280UL   //    983,040  Hq0 -> aq
#define O_HP1    32440320UL   //  9,830,400
#define O_HQ1    42270720UL   //    983,040
#define O_WT0    43253760UL   //    176,128
#define O_WT1    43429888UL   //    131,072
#define O_WTQ    43560960UL   //     65,536
#define O_WTP    43626496UL   //     65,536
#define O_WTZ    43692032UL   //    131,072
#define O_P0HH   43823104UL   //     32,768 u32
#define O_P1HH   43855872UL
#define O_PMHH   43888640UL
#define O_PMWH   43921408UL   //     16,384 u32

extern "C" void kernel_launch(void* const* d_in, const int* in_sizes, int n_in,
                              void* d_out, int out_size, void* d_ws, size_t ws_size,
                              hipStream_t stream)
{
    const float* passage  = (const float*)d_in[0];
    const float* question = (const float*)d_in[1];
    const float* mask_p   = (const float*)d_in[2];
    const float* mask_q   = (const float*)d_in[3];
    const float* pre0_Wih = (const float*)d_in[4];
    const float* pre0_Whh = (const float*)d_in[5];
    const float* pre0_b   = (const float*)d_in[6];
    const float* pre1_Wih = (const float*)d_in[7];
    const float* pre1_Whh = (const float*)d_in[8];
    const float* pre1_b   = (const float*)d_in[9];
    const float* mq_Wq    = (const float*)d_in[10];
    const float* mq_Wp    = (const float*)d_in[11];
    const float* mq_bp    = (const float*)d_in[12];
    const float* mq_Wh    = (const float*)d_in[13];
    const float* mq_Wa    = (const float*)d_in[14];
    // d_in[15] = mq_ba: softmax-invariant, skipped
    const float* mq_Wih   = (const float*)d_in[16];
    const float* mq_Whh   = (const float*)d_in[17];
    const float* mq_b     = (const float*)d_in[18];

    float* ws = (float*)d_ws;
    float* bufX  = ws + O_BUFX;
    float* bufXq = ws + O_BUFXQ;
    float* Hp0   = ws + O_HP0;
    float* Hq0   = ws + O_HQ0;
    float* Hp1   = ws + O_HP1;
    float* Hq1   = ws + O_HQ1;
    float* WT0   = ws + O_WT0;
    float* WT1   = ws + O_WT1;
    float* WTq   = ws + O_WTQ;
    float* WTp   = ws + O_WTP;
    float* WTz   = ws + O_WTZ;
    u32*   P0hh  = (u32*)(ws + O_P0HH);
    u32*   P1hh  = (u32*)(ws + O_P1HH);
    u32*   PMhh  = (u32*)(ws + O_PMHH);
    u32*   PMwh  = (u32*)(ws + O_PMWH);
    float* ap = Hp0;   // Hp0 dead after proj1
    float* aq = Hq0;
    float* Zp = bufX;  // Xp1 dead after rec1
    float* Yq = bufXq; // Xq1 dead after rec1

    prep_kernel<<<688, 256, 0, stream>>>(pre0_Wih, pre0_Whh, pre1_Wih, pre1_Whh,
                                         mq_Wq, mq_Wp, mq_Wh, mq_Whh,
                                         WT0, WT1, WTq, WTp, WTz, mq_Wih,
                                         P0hh, P1hh, PMhh, PMwh);
    proj_kernel<EMB, 512><<<660, 512, 0, stream>>>(passage, WT0, pre0_b, bufX, TP,
                                                   question, WT0, pre0_b, bufXq);
    rec_pre_kernel<<<256, 384, 0, stream>>>(bufX, bufXq, P0hh, mask_p, mask_q, Hp0, Hq0);
    proj_kernel<256, 512><<<660, 512, 0, stream>>>(Hp0, WT1, pre1_b, bufX, TP,
                                                   Hq0, WT1, pre1_b, bufXq);
    rec_pre_kernel<<<256, 384, 0, stream>>>(bufX, bufXq, P1hh, mask_p, mask_q, Hp1, Hq1);
    proj_kernel<256, 256><<<660, 256, 0, stream>>>(Hp1, WTp, mq_bp, ap, TP,
                                                   Hq1, WTq, nullptr, aq);
    proj_kernel<256, 512><<<600, 512, 0, stream>>>(Hp1, WTz, mq_b, Zp, TP,
                                                   nullptr, nullptr, nullptr, nullptr);
    yq_kernel<<<60, 512, 0, stream>>>(Hq1, mq_Wih, Yq);
    match_kernel<<<128, 512, 0, stream>>>(ap, aq, Zp, Yq, mq_Wa, mask_p,
                                          PMwh, PMhh, (float*)d_out);
}

// Round 5
// 8446.136 us; speedup vs baseline: 1.2205x; 1.0032x over previous
//
#include <hip/hip_runtime.h>

typedef unsigned int u32;
typedef _Float16 f16x2 __attribute__((ext_vector_type(2)));

#define TP 600
#define TQ 60
#define BB 64
#define EMB 344
#define HH 256
#define H2 128
#define GG 512

// ---------- fast math helpers ----------
__device__ __forceinline__ float exp2_fast(float x){
#if __has_builtin(__builtin_amdgcn_exp2f)
    return __builtin_amdgcn_exp2f(x);
#else
    return exp2f(x);
#endif
}
__device__ __forceinline__ float rcp_fast(float x){
#if __has_builtin(__builtin_amdgcn_rcpf)
    return __builtin_amdgcn_rcpf(x);
#else
    return 1.0f / x;
#endif
}
__device__ __forceinline__ float sigm_fast(float x){
    return rcp_fast(1.f + exp2_fast(-1.44269504f * x));
}
__device__ __forceinline__ float tanh_fast(float x){
    return 1.f - 2.f * rcp_fast(1.f + exp2_fast(2.88539008f * x));
}
__device__ __forceinline__ float dot2x(u32 w, u32 h, float acc){
    f16x2 wv = __builtin_bit_cast(f16x2, w);
    f16x2 hv = __builtin_bit_cast(f16x2, h);
    acc = fmaf((float)wv.x, (float)hv.x, acc);
    acc = fmaf((float)wv.y, (float)hv.y, acc);
    return acc;
}
__device__ __forceinline__ u32 pack2(float a, float b){
    f16x2 v; v.x = (_Float16)a; v.y = (_Float16)b;
    return __builtin_bit_cast(u32, v);
}
// wave-wide broadcast of lane l's copy of v (VALU pipe, not LDS pipe)
__device__ __forceinline__ u32 lane_bcast(u32 v, int l){
    return (u32)__builtin_amdgcn_readlane((int)v, l);
}

// ---------- prep: transpose weights (fp32 WT4 layout) + fp16 packing ----------
__global__ void prep_kernel(const float* __restrict__ pre0_Wih, const float* __restrict__ pre0_Whh,
                            const float* __restrict__ pre1_Wih, const float* __restrict__ pre1_Whh,
                            const float* __restrict__ Wq, const float* __restrict__ Wp,
                            const float* __restrict__ Whm,
                            const float* __restrict__ Whhm,
                            float* __restrict__ WT0, float* __restrict__ WT1,
                            float* __restrict__ WTq, float* __restrict__ WTp,
                            float* __restrict__ WTz, const float* __restrict__ Wihm,
                            u32* __restrict__ P0hh, u32* __restrict__ P1hh,
                            u32* __restrict__ PMhh, u32* __restrict__ PMwh)
{
    int g = blockIdx.x * blockDim.x + threadIdx.x;
    int gs = gridDim.x * blockDim.x;
    for (int idx = g; idx < 512*344; idx += gs) {
        int j = idx / 344, k = idx - j*344;
        WT0[((k>>2)*512 + j)*4 + (k&3)] = pre0_Wih[idx];
    }
    for (int idx = g; idx < 512*256; idx += gs) {
        int j = idx >> 8, k = idx & 255;
        WT1[((k>>2)*512 + j)*4 + (k&3)] = pre1_Wih[idx];
    }
    for (int idx = g; idx < 256*256; idx += gs) {
        int j = idx >> 8, k = idx & 255;
        WTq[((k>>2)*256 + j)*4 + (k&3)] = Wq[idx];
        WTp[((k>>2)*256 + j)*4 + (k&3)] = Wp[idx];
    }
    for (int idx = g; idx < 512*256; idx += gs) {
        int j = idx >> 8, k = idx & 255;
        WTz[((k>>2)*512 + j)*4 + (k&3)] = Wihm[j*512 + k];
    }
    for (int idx = g; idx < 64*512; idx += gs) {
        int k2 = idx >> 9, j = idx & 511;
        P0hh[idx] = pack2(pre0_Whh[j*128 + 2*k2], pre0_Whh[j*128 + 2*k2 + 1]);
        P1hh[idx] = pack2(pre1_Whh[j*128 + 2*k2], pre1_Whh[j*128 + 2*k2 + 1]);
        PMhh[idx] = pack2(Whhm[j*128 + 2*k2], Whhm[j*128 + 2*k2 + 1]);
    }
    for (int idx = g; idx < 64*256; idx += gs) {
        int k2 = idx >> 8, j = idx & 255;
        PMwh[idx] = pack2(Whm[j*128 + 2*k2], Whm[j*128 + 2*k2 + 1]);
    }
}

// ---------- batched projection ----------
template<int K, int M>
__global__ __launch_bounds__(M)
void proj_kernel(const float* __restrict__ X0, const float* __restrict__ W0,
                 const float* __restrict__ b0, float* __restrict__ C0, int T0,
                 const float* __restrict__ X1, const float* __restrict__ W1,
                 const float* __restrict__ b1, float* __restrict__ C1)
{
    __shared__ float Xs[K*68];
    int t = blockIdx.x;
    const float* X; const float* W; const float* bias; float* C; int trow;
    if (t < T0) { X = X0; W = W0; bias = b0; C = C0; trow = t; }
    else        { X = X1; W = W1; bias = b1; C = C1; trow = t - T0; }
    int j = threadIdx.x;
    for (int b = 0; b < 64; ++b) {
        for (int k = j; k < K; k += M)
            Xs[k*68 + b] = X[(trow*64 + b)*K + k];
    }
    __syncthreads();
    float acc[64];
    float binit = bias ? bias[j] : 0.f;
    #pragma unroll
    for (int b = 0; b < 64; ++b) acc[b] = binit;
    const float4* W4 = (const float4*)W;
    for (int k4 = 0; k4 < K/4; ++k4) {
        float4 w4 = W4[k4*M + j];
        float wv[4] = {w4.x, w4.y, w4.z, w4.w};
        #pragma unroll
        for (int kk = 0; kk < 4; ++kk) {
            int k = 4*k4 + kk;
            #pragma unroll
            for (int b4 = 0; b4 < 16; ++b4) {
                float4 x4 = *((const float4*)&Xs[k*68 + 4*b4]);
                acc[4*b4+0] = fmaf(wv[kk], x4.x, acc[4*b4+0]);
                acc[4*b4+1] = fmaf(wv[kk], x4.y, acc[4*b4+1]);
                acc[4*b4+2] = fmaf(wv[kk], x4.z, acc[4*b4+2]);
                acc[4*b4+3] = fmaf(wv[kk], x4.w, acc[4*b4+3]);
            }
        }
    }
    for (int b = 0; b < 64; ++b)
        C[(trow*64 + b)*M + j] = acc[b];
}

// ---------- Yq precompute ----------
__global__ __launch_bounds__(512)
void yq_kernel(const float* __restrict__ Hq1, const float* __restrict__ Wihm,
               float* __restrict__ Yq)
{
    __shared__ float Xs[256*68];
    int tq = blockIdx.x;
    int j = threadIdx.x;
    for (int b = 0; b < 64; ++b) {
        for (int k = j; k < 256; k += 512)
            Xs[k*68 + b] = Hq1[(tq*64 + b)*256 + k];
    }
    __syncthreads();
    float acc[64];
    #pragma unroll
    for (int b = 0; b < 64; ++b) acc[b] = 0.f;
    const float4* W4 = (const float4*)(Wihm + j*512 + 256);
    for (int k4 = 0; k4 < 64; ++k4) {
        float4 w4 = W4[k4];
        float wv[4] = {w4.x, w4.y, w4.z, w4.w};
        #pragma unroll
        for (int kk = 0; kk < 4; ++kk) {
            int k = 4*k4 + kk;
            #pragma unroll
            for (int b4 = 0; b4 < 16; ++b4) {
                float4 x4 = *((const float4*)&Xs[k*68 + 4*b4]);
                acc[4*b4+0] = fmaf(wv[kk], x4.x, acc[4*b4+0]);
                acc[4*b4+1] = fmaf(wv[kk], x4.y, acc[4*b4+1]);
                acc[4*b4+2] = fmaf(wv[kk], x4.z, acc[4*b4+2]);
                acc[4*b4+3] = fmaf(wv[kk], x4.w, acc[4*b4+3]);
            }
        }
    }
    for (int b = 0; b < 64; ++b)
        Yq[(tq*64 + b)*512 + j] = acc[b];
}

// ---------- pre-BiLSTM recurrence (h discarded; c masked; h = tanh(c)) ----------
// grid 256 = 1 block/CU; no min-waves bound -> full register budget, no spill
__global__ __launch_bounds__(384)
void rec_pre_kernel(const float* __restrict__ Xp, const float* __restrict__ Xq,
                    const u32* __restrict__ Whh,
                    const float* __restrict__ mask_p, const float* __restrict__ mask_q,
                    float* __restrict__ Hp, float* __restrict__ Hq)
{
    int bid = blockIdx.x;
    int sub = bid & 127; int b = sub >> 1; int dir = sub & 1;
    const float* X; const float* mask; float* Hout; int T;
    if (bid < 128) { X = Xp; mask = mask_p; Hout = Hp; T = TP; }
    else           { X = Xq; mask = mask_q; Hout = Hq; T = TQ; }
    int j = threadIdx.x;
    __shared__ __align__(16) _Float16 h16[128];
    __shared__ float gates[384];
    u32 w[64];
    #pragma unroll
    for (int q = 0; q < 64; ++q) w[q] = Whh[q*512 + j];
    if (j < 128) h16[j] = (_Float16)0.f;
    float c = 0.f;
    int ti0 = dir ? (T-1) : 0;
    float x_c = X[(ti0*64 + b)*512 + j];
    float m_c = mask[ti0*64 + b];
    int cls = j >> 7;                            // 0:i 1:f 2:g (wave-uniform)
    __syncthreads();
    const u32* h32 = (const u32*)h16;
    for (int s = 0; s < T; ++s) {
        int ti = dir ? (T-1-s) : s;
        int s1 = (s+1 < T) ? (s+1) : s;
        int tn = dir ? (T-1-s1) : s1;
        float x_n = X[(tn*64 + b)*512 + j];
        float m_n = mask[tn*64 + b];
        // cooperative h read: lane l holds pair l; broadcast via readlane
        u32 hp = h32[j & 63];
        float a0 = x_c, a1 = 0.f, a2 = 0.f, a3 = 0.f;
        #pragma unroll
        for (int q = 0; q < 64; q += 4) {
            u32 h0 = lane_bcast(hp, q),   h1 = lane_bcast(hp, q+1);
            u32 h2v = lane_bcast(hp, q+2), h3 = lane_bcast(hp, q+3);
            a0 = dot2x(w[q],   h0,  a0);
            a1 = dot2x(w[q+1], h1,  a1);
            a2 = dot2x(w[q+2], h2v, a2);
            a3 = dot2x(w[q+3], h3,  a3);
        }
        float g = (a0 + a1) + (a2 + a3);
        gates[j] = (cls == 2) ? tanh_fast(g) : sigm_fast(g);
        __syncthreads();
        if (j < 128) {
            float gi = gates[j], gf = gates[128+j], gg = gates[256+j];
            c = gf*c + gi*gg;
            c *= m_c;
            float h = tanh_fast(c);
            h16[j] = (_Float16)h;
            Hout[(ti*64 + b)*256 + dir*128 + j] = h;
        }
        __syncthreads();
        x_c = x_n; m_c = m_n;
    }
}

// ---------- Match-LSTM recurrence: one block per (b, dir) ----------
// grid 128 on 256 CUs = 1 block/CU regardless; no min-waves bound -> up to 256
// VGPRs/wave so whh[64]+wh[64]+wa_reg[16] (~190 regs) stay in registers.
// Round-4's __launch_bounds__(512,2) pinned VGPRs to 128 and spilled the
// weight arrays to scratch, reloading ~128 dwords/thread EVERY step.
__global__ __launch_bounds__(512)
void match_kernel(const float* __restrict__ ap,   // [600][64][256]
                  const float* __restrict__ aqg,  // [60][64][256]
                  const float* __restrict__ Zp,   // [600][64][512]
                  const float* __restrict__ Yq,   // [60][64][512]
                  const float* __restrict__ Wa,   // [256]
                  const float* __restrict__ mask_p,
                  const u32* __restrict__ PMwh,   // [64][256] packed Wh
                  const u32* __restrict__ PMhh,   // [64][512] packed Whh
                  float* __restrict__ out)        // [600][64][256]
{
    int bid = blockIdx.x; int b = bid >> 1; int dir = bid & 1;
    int tid = threadIdx.x;
    __shared__ __align__(16) uint4 Yq4s[8*512];      // [r4][j]: pairs (4r4..4r4+3) of tq
    __shared__ __align__(16) u32 aq16[64*132];       // [tq][pair p], row stride 132
    __shared__ float gates[512];
    __shared__ __align__(16) u32 sumt16[160];        // [sb][20]: pairs [16sb..16sb+16)
    __shared__ __align__(16) _Float16 h16[128];
    __shared__ __align__(16) _Float16 e16[64];

    // ---- startup staging ----
    for (int idx = tid; idx < 60*128; idx += 512) {
        int tq = idx >> 7, p = idx & 127;
        float2 a = *(const float2*)&aqg[(tq*64 + b)*256 + 2*p];
        aq16[tq*132 + p] = pack2(a.x, a.y);
    }
    for (int idx = tid; idx < 4*132; idx += 512)     // zero pad rows 60..63
        aq16[60*132 + idx] = 0u;
    #pragma unroll
    for (int r4 = 0; r4 < 8; ++r4) {
        float v[8];
        #pragma unroll
        for (int k = 0; k < 8; ++k) {
            int tq = 8*r4 + k;
            v[k] = (tq < 60) ? Yq[(tq*64 + b)*512 + tid] : 0.f;
        }
        Yq4s[r4*512 + tid] = make_uint4(pack2(v[0],v[1]), pack2(v[2],v[3]),
                                        pack2(v[4],v[5]), pack2(v[6],v[7]));
    }
    if (tid < 128) h16[tid] = (_Float16)0.f;

    // per-lane wa slice registers (pairs [16sb..16sb+16))
    int sb = tid & 7;
    u32 wa_reg[16];
    #pragma unroll
    for (int i = 0; i < 16; ++i) {
        float2 w2 = *(const float2*)&Wa[32*sb + 2*i];
        wa_reg[i] = pack2(w2.x, w2.y);
    }
    u32 whh[64];
    #pragma unroll
    for (int q = 0; q < 64; ++q) whh[q] = PMhh[q*512 + tid];
    u32 wh[64];
    {
        int jw = tid & 255;
        #pragma unroll
        for (int q = 0; q < 64; ++q) wh[q] = PMwh[q*256 + jw];
    }
    float c = 0.f;
    int ti0 = dir ? (TP-1) : 0;
    float zp_c = Zp[(ti0*64 + b)*512 + tid];
    float ap_c = (tid < 256) ? ap[(ti0*64 + b)*256 + tid] : 0.f;
    float m_c  = mask_p[ti0*64 + b];
    int cls = tid >> 7;                               // gate class, wave-uniform
    const u32 ONE2 = 0x3C003C00u;                     // fp16 (1.0, 1.0)
    __syncthreads();

    const u32* h32 = (const u32*)h16;
    const u32* e32 = (const u32*)e16;

    for (int s = 0; s < TP; ++s) {
        int ti = dir ? (TP-1-s) : s;
        int s1 = (s+1 < TP) ? (s+1) : s;
        int tn = dir ? (TP-1-s1) : s1;

        // ---- P1: hWhh[tid] (kept in reg) and sumt = ap + h@Wh.T (tid<256) ----
        u32 hp = h32[tid & 63];                       // coop read: lane l holds pair l
        float w0 = 0.f, w1 = 0.f, w2a = 0.f, w3a = 0.f;
        if (tid < 256) {
            float s0 = ap_c, s1a = 0.f, s2 = 0.f, s3 = 0.f;
            #pragma unroll
            for (int q = 0; q < 64; q += 4) {
                u32 h0 = lane_bcast(hp, q),   u1 = lane_bcast(hp, q+1);
                u32 h2v = lane_bcast(hp, q+2), h3 = lane_bcast(hp, q+3);
                w0  = dot2x(whh[q],   h0,  w0);  s0  = dot2x(wh[q],   h0,  s0);
                w1  = dot2x(whh[q+1], u1,  w1);  s1a = dot2x(wh[q+1], u1,  s1a);
                w2a = dot2x(whh[q+2], h2v, w2a); s2  = dot2x(wh[q+2], h2v, s2);
                w3a = dot2x(whh[q+3], h3,  w3a); s3  = dot2x(wh[q+3], h3,  s3);
            }
            float st = (s0 + s1a) + (s2 + s3);
            float so = __shfl_xor(st, 1);
            if ((tid & 1) == 0) {
                int p = tid >> 1;
                sumt16[(p >> 4)*20 + (p & 15)] = pack2(st, so);
            }
        } else {
            #pragma unroll
            for (int q = 0; q < 64; q += 4) {
                u32 h0 = lane_bcast(hp, q),   u1 = lane_bcast(hp, q+1);
                u32 h2v = lane_bcast(hp, q+2), h3 = lane_bcast(hp, q+3);
                w0  = dot2x(whh[q],   h0,  w0);
                w1  = dot2x(whh[q+1], u1,  w1);
                w2a = dot2x(whh[q+2], h2v, w2a);
                w3a = dot2x(whh[q+3], h3,  w3a);
            }
        }
        float hwhh = (w0 + w1) + (w2a + w3a);
        __syncthreads();                              // bar1

        // prefetch next step rows (drained at bar2; covered by P2 transcendentals)
        float zp_n = Zp[(tn*64 + b)*512 + tid];
        float ap_n = (tid < 256) ? ap[(tn*64 + b)*256 + tid] : 0.f;
        float m_n  = mask_p[tn*64 + b];

        // ---- P2: scores -> e16 (clamped, fp16) ----
        {
            int tq = tid >> 3;
            const uint4* sv4 = (const uint4*)&sumt16[sb*20];
            const uint4* av4 = (const uint4*)&aq16[tq*132 + 16*sb];
            uint4 sv0 = sv4[0], sv1 = sv4[1], sv2 = sv4[2], sv3 = sv4[3];
            uint4 av0 = av4[0], av1 = av4[1], av2 = av4[2], av3 = av4[3];
            float p0 = 0.f, p1 = 0.f, p2 = 0.f, p3 = 0.f;
            u32 sa[16] = {sv0.x,sv0.y,sv0.z,sv0.w, sv1.x,sv1.y,sv1.z,sv1.w,
                          sv2.x,sv2.y,sv2.z,sv2.w, sv3.x,sv3.y,sv3.z,sv3.w};
            u32 aa[16] = {av0.x,av0.y,av0.z,av0.w, av1.x,av1.y,av1.z,av1.w,
                          av2.x,av2.y,av2.z,av2.w, av3.x,av3.y,av3.z,av3.w};
            #pragma unroll
            for (int i = 0; i < 16; i += 4) {
                #pragma unroll
                for (int k = 0; k < 4; ++k) {
                    f16x2 av = __builtin_bit_cast(f16x2, aa[i+k]);
                    f16x2 sv = __builtin_bit_cast(f16x2, sa[i+k]);
                    f16x2 wv = __builtin_bit_cast(f16x2, wa_reg[i+k]);
                    float& pa = (k & 1) ? p2 : p0;
                    float& pb = (k & 1) ? p3 : p1;
                    pa = fmaf((float)wv.x, tanh_fast((float)av.x + (float)sv.x), pa);
                    pb = fmaf((float)wv.y, tanh_fast((float)av.y + (float)sv.y), pb);
                }
            }
            float part = (p0 + p1) + (p2 + p3);
            part += __shfl_xor(part, 1);
            part += __shfl_xor(part, 2);
            part += __shfl_xor(part, 4);
            float sc = fminf(9.f, fmaxf(-9.f, part));
            float e = exp2_fast(sc * 1.44269504f);
            if (tq >= 60) e = 0.f;
            if (sb == 0) e16[tq] = (_Float16)e;
        }
        __syncthreads();                              // bar2

        // ---- P4: gates = Zp + rn*(sum_tq e*Yq) + hWhh ; nonlinearity fused ----
        {
            u32 ep = e32[tid & 31];                   // coop read: lane l holds e-pair l
            float y0 = 0.f, y1 = 0.f, S0 = 0.f, S1 = 0.f;
            #pragma unroll
            for (int r4 = 0; r4 < 8; ++r4) {
                uint4 yv = Yq4s[r4*512 + tid];
                u32 e0 = lane_bcast(ep, 4*r4+0), e1 = lane_bcast(ep, 4*r4+1);
                u32 e2 = lane_bcast(ep, 4*r4+2), e3 = lane_bcast(ep, 4*r4+3);
                y0 = dot2x(yv.x, e0, y0); S0 = dot2x(ONE2, e0, S0);
                y1 = dot2x(yv.y, e1, y1); S1 = dot2x(ONE2, e1, S1);
                y0 = dot2x(yv.z, e2, y0); S0 = dot2x(ONE2, e2, S0);
                y1 = dot2x(yv.w, e3, y1); S1 = dot2x(ONE2, e3, S1);
            }
            float rn = rcp_fast(S0 + S1);
            float g = zp_c + rn * (y0 + y1) + hwhh;
            gates[tid] = (cls == 2) ? tanh_fast(g) : sigm_fast(g);
        }
        __syncthreads();                              // bar3

        // ---- P5: cell; h,c masked after cell ----
        if (tid < 128) {
            float gi = gates[tid], gf = gates[128+tid], gg = gates[256+tid], go = gates[384+tid];
            c = gf*c + gi*gg;
            float h = go * tanh_fast(c);
            h *= m_c; c *= m_c;
            h16[tid] = (_Float16)h;
            out[(ti*64 + b)*256 + dir*128 + tid] = h;
        }
        __syncthreads();                              // bar4 (h ready)
        zp_c = zp_n; ap_c = ap_n; m_c = m_n;
    }
}

// ---------- workspace layout (floats) ----------
#define O_BUFX   0UL          // 19,660,800  Xp0 -> Xp1 -> Zp
#define O_BUFXQ  19660800UL   //  1,966,080  Xq0 -> Xq1 -> Yq
#define O_HP0    21626880UL   //  9,830,400  Hp0 -> ap
#define O_HQ0    31457280UL   //    983,040  Hq0 -> aq
#define O_HP1    32440320UL   //  9,830,400
#define O_HQ1    42270720UL   //    983,040
#define O_WT0    43253760UL   //    176,128
#define O_WT1    43429888UL   //    131,072
#define O_WTQ    43560960UL   //     65,536
#define O_WTP    43626496UL   //     65,536
#define O_WTZ    43692032UL   //    131,072
#define O_P0HH   43823104UL   //     32,768 u32
#define O_P1HH   43855872UL
#define O_PMHH   43888640UL
#define O_PMWH   43921408UL   //     16,384 u32

extern "C" void kernel_launch(void* const* d_in, const int* in_sizes, int n_in,
                              void* d_out, int out_size, void* d_ws, size_t ws_size,
                              hipStream_t stream)
{
    const float* passage  = (const float*)d_in[0];
    const float* question = (const float*)d_in[1];
    const float* mask_p   = (const float*)d_in[2];
    const float* mask_q   = (const float*)d_in[3];
    const float* pre0_Wih = (const float*)d_in[4];
    const float* pre0_Whh = (const float*)d_in[5];
    const float* pre0_b   = (const float*)d_in[6];
    const float* pre1_Wih = (const float*)d_in[7];
    const float* pre1_Whh = (const float*)d_in[8];
    const float* pre1_b   = (const float*)d_in[9];
    const float* mq_Wq    = (const float*)d_in[10];
    const float* mq_Wp    = (const float*)d_in[11];
    const float* mq_bp    = (const float*)d_in[12];
    const float* mq_Wh    = (const float*)d_in[13];
    const float* mq_Wa    = (const float*)d_in[14];
    // d_in[15] = mq_ba: softmax-invariant, skipped
    const float* mq_Wih   = (const float*)d_in[16];
    const float* mq_Whh   = (const float*)d_in[17];
    const float* mq_b     = (const float*)d_in[18];

    float* ws = (float*)d_ws;
    float* bufX  = ws + O_BUFX;
    float* bufXq = ws + O_BUFXQ;
    float* Hp0   = ws + O_HP0;
    float* Hq0   = ws + O_HQ0;
    float* Hp1   = ws + O_HP1;
    float* Hq1   = ws + O_HQ1;
    float* WT0   = ws + O_WT0;
    float* WT1   = ws + O_WT1;
    float* WTq   = ws + O_WTQ;
    float* WTp   = ws + O_WTP;
    float* WTz   = ws + O_WTZ;
    u32*   P0hh  = (u32*)(ws + O_P0HH);
    u32*   P1hh  = (u32*)(ws + O_P1HH);
    u32*   PMhh  = (u32*)(ws + O_PMHH);
    u32*   PMwh  = (u32*)(ws + O_PMWH);
    float* ap = Hp0;   // Hp0 dead after proj1
    float* aq = Hq0;
    float* Zp = bufX;  // Xp1 dead after rec1
    float* Yq = bufXq; // Xq1 dead after rec1

    prep_kernel<<<688, 256, 0, stream>>>(pre0_Wih, pre0_Whh, pre1_Wih, pre1_Whh,
                                         mq_Wq, mq_Wp, mq_Wh, mq_Whh,
                                         WT0, WT1, WTq, WTp, WTz, mq_Wih,
                                         P0hh, P1hh, PMhh, PMwh);
    proj_kernel<EMB, 512><<<660, 512, 0, stream>>>(passage, WT0, pre0_b, bufX, TP,
                                                   question, WT0, pre0_b, bufXq);
    rec_pre_kernel<<<256, 384, 0, stream>>>(bufX, bufXq, P0hh, mask_p, mask_q, Hp0, Hq0);
    proj_kernel<256, 512><<<660, 512, 0, stream>>>(Hp0, WT1, pre1_b, bufX, TP,
                                                   Hq0, WT1, pre1_b, bufXq);
    rec_pre_kernel<<<256, 384, 0, stream>>>(bufX, bufXq, P1hh, mask_p, mask_q, Hp1, Hq1);
    proj_kernel<256, 256><<<660, 256, 0, stream>>>(Hp1, WTp, mq_bp, ap, TP,
                                                   Hq1, WTq, nullptr, aq);
    proj_kernel<256, 512><<<600, 512, 0, stream>>>(Hp1, WTz, mq_b, Zp, TP,
                                                   nullptr, nullptr, nullptr, nullptr);
    yq_kernel<<<60, 512, 0, stream>>>(Hq1, mq_Wih, Yq);
    match_kernel<<<128, 512, 0, stream>>>(ap, aq, Zp, Yq, mq_Wa, mask_p,
                                          PMwh, PMhh, (float*)d_out);
}

// Round 6
// 3742.117 us; speedup vs baseline: 2.7548x; 2.2570x over previous
//
#include <hip/hip_runtime.h>

typedef unsigned int u32;
typedef _Float16 f16x2 __attribute__((ext_vector_type(2)));

#define TP 600
#define TQ 60
#define BB 64
#define EMB 344
#define HH 256
#define H2 128
#define GG 512

// ---------- fast math helpers ----------
__device__ __forceinline__ float exp2_fast(float x){
#if __has_builtin(__builtin_amdgcn_exp2f)
    return __builtin_amdgcn_exp2f(x);
#else
    return exp2f(x);
#endif
}
__device__ __forceinline__ float rcp_fast(float x){
#if __has_builtin(__builtin_amdgcn_rcpf)
    return __builtin_amdgcn_rcpf(x);
#else
    return 1.0f / x;
#endif
}
__device__ __forceinline__ float sigm_fast(float x){
    return rcp_fast(1.f + exp2_fast(-1.44269504f * x));
}
__device__ __forceinline__ float tanh_fast(float x){
    return 1.f - 2.f * rcp_fast(1.f + exp2_fast(2.88539008f * x));
}
__device__ __forceinline__ float dot2x(u32 w, u32 h, float acc){
    f16x2 wv = __builtin_bit_cast(f16x2, w);
    f16x2 hv = __builtin_bit_cast(f16x2, h);
    acc = fmaf((float)wv.x, (float)hv.x, acc);
    acc = fmaf((float)wv.y, (float)hv.y, acc);
    return acc;
}
// v_dot2_f32_f16: 2 fp16 MACs, fp32 accumulate, ONE instruction
__device__ __forceinline__ float dot2f(u32 w, u32 h, float acc){
#if __has_builtin(__builtin_amdgcn_fdot2)
    return __builtin_amdgcn_fdot2(__builtin_bit_cast(f16x2, w),
                                  __builtin_bit_cast(f16x2, h), acc, false);
#else
    return dot2x(w, h, acc);
#endif
}
__device__ __forceinline__ u32 pack2(float a, float b){
    f16x2 v; v.x = (_Float16)a; v.y = (_Float16)b;
    return __builtin_bit_cast(u32, v);
}
// wave-wide broadcast of lane l's copy of v (VALU pipe, not LDS pipe)
__device__ __forceinline__ u32 lane_bcast(u32 v, int l){
    return (u32)__builtin_amdgcn_readlane((int)v, l);
}

// ---------- prep: transpose weights (fp32 WT4 layout) + fp16 packing ----------
__global__ void prep_kernel(const float* __restrict__ pre0_Wih, const float* __restrict__ pre0_Whh,
                            const float* __restrict__ pre1_Wih, const float* __restrict__ pre1_Whh,
                            const float* __restrict__ Wq, const float* __restrict__ Wp,
                            const float* __restrict__ Whm,
                            const float* __restrict__ Whhm,
                            float* __restrict__ WT0, float* __restrict__ WT1,
                            float* __restrict__ WTq, float* __restrict__ WTp,
                            float* __restrict__ WTz, const float* __restrict__ Wihm,
                            u32* __restrict__ P0hh, u32* __restrict__ P1hh,
                            u32* __restrict__ PMhh, u32* __restrict__ PMwh)
{
    int g = blockIdx.x * blockDim.x + threadIdx.x;
    int gs = gridDim.x * blockDim.x;
    for (int idx = g; idx < 512*344; idx += gs) {
        int j = idx / 344, k = idx - j*344;
        WT0[((k>>2)*512 + j)*4 + (k&3)] = pre0_Wih[idx];
    }
    for (int idx = g; idx < 512*256; idx += gs) {
        int j = idx >> 8, k = idx & 255;
        WT1[((k>>2)*512 + j)*4 + (k&3)] = pre1_Wih[idx];
    }
    for (int idx = g; idx < 256*256; idx += gs) {
        int j = idx >> 8, k = idx & 255;
        WTq[((k>>2)*256 + j)*4 + (k&3)] = Wq[idx];
        WTp[((k>>2)*256 + j)*4 + (k&3)] = Wp[idx];
    }
    for (int idx = g; idx < 512*256; idx += gs) {
        int j = idx >> 8, k = idx & 255;
        WTz[((k>>2)*512 + j)*4 + (k&3)] = Wihm[j*512 + k];
    }
    for (int idx = g; idx < 64*512; idx += gs) {
        int k2 = idx >> 9, j = idx & 511;
        P0hh[idx] = pack2(pre0_Whh[j*128 + 2*k2], pre0_Whh[j*128 + 2*k2 + 1]);
        P1hh[idx] = pack2(pre1_Whh[j*128 + 2*k2], pre1_Whh[j*128 + 2*k2 + 1]);
        PMhh[idx] = pack2(Whhm[j*128 + 2*k2], Whhm[j*128 + 2*k2 + 1]);
    }
    for (int idx = g; idx < 64*256; idx += gs) {
        int k2 = idx >> 8, j = idx & 255;
        PMwh[idx] = pack2(Whm[j*128 + 2*k2], Whm[j*128 + 2*k2 + 1]);
    }
}

// ---------- batched projection ----------
template<int K, int M>
__global__ __launch_bounds__(M)
void proj_kernel(const float* __restrict__ X0, const float* __restrict__ W0,
                 const float* __restrict__ b0, float* __restrict__ C0, int T0,
                 const float* __restrict__ X1, const float* __restrict__ W1,
                 const float* __restrict__ b1, float* __restrict__ C1)
{
    __shared__ float Xs[K*68];
    int t = blockIdx.x;
    const float* X; const float* W; const float* bias; float* C; int trow;
    if (t < T0) { X = X0; W = W0; bias = b0; C = C0; trow = t; }
    else        { X = X1; W = W1; bias = b1; C = C1; trow = t - T0; }
    int j = threadIdx.x;
    for (int b = 0; b < 64; ++b) {
        for (int k = j; k < K; k += M)
            Xs[k*68 + b] = X[(trow*64 + b)*K + k];
    }
    __syncthreads();
    float acc[64];
    float binit = bias ? bias[j] : 0.f;
    #pragma unroll
    for (int b = 0; b < 64; ++b) acc[b] = binit;
    const float4* W4 = (const float4*)W;
    for (int k4 = 0; k4 < K/4; ++k4) {
        float4 w4 = W4[k4*M + j];
        float wv[4] = {w4.x, w4.y, w4.z, w4.w};
        #pragma unroll
        for (int kk = 0; kk < 4; ++kk) {
            int k = 4*k4 + kk;
            #pragma unroll
            for (int b4 = 0; b4 < 16; ++b4) {
                float4 x4 = *((const float4*)&Xs[k*68 + 4*b4]);
                acc[4*b4+0] = fmaf(wv[kk], x4.x, acc[4*b4+0]);
                acc[4*b4+1] = fmaf(wv[kk], x4.y, acc[4*b4+1]);
                acc[4*b4+2] = fmaf(wv[kk], x4.z, acc[4*b4+2]);
                acc[4*b4+3] = fmaf(wv[kk], x4.w, acc[4*b4+3]);
            }
        }
    }
    for (int b = 0; b < 64; ++b)
        C[(trow*64 + b)*M + j] = acc[b];
}

// ---------- Yq precompute ----------
__global__ __launch_bounds__(512)
void yq_kernel(const float* __restrict__ Hq1, const float* __restrict__ Wihm,
               float* __restrict__ Yq)
{
    __shared__ float Xs[256*68];
    int tq = blockIdx.x;
    int j = threadIdx.x;
    for (int b = 0; b < 64; ++b) {
        for (int k = j; k < 256; k += 512)
            Xs[k*68 + b] = Hq1[(tq*64 + b)*256 + k];
    }
    __syncthreads();
    float acc[64];
    #pragma unroll
    for (int b = 0; b < 64; ++b) acc[b] = 0.f;
    const float4* W4 = (const float4*)(Wihm + j*512 + 256);
    for (int k4 = 0; k4 < 64; ++k4) {
        float4 w4 = W4[k4];
        float wv[4] = {w4.x, w4.y, w4.z, w4.w};
        #pragma unroll
        for (int kk = 0; kk < 4; ++kk) {
            int k = 4*k4 + kk;
            #pragma unroll
            for (int b4 = 0; b4 < 16; ++b4) {
                float4 x4 = *((const float4*)&Xs[k*68 + 4*b4]);
                acc[4*b4+0] = fmaf(wv[kk], x4.x, acc[4*b4+0]);
                acc[4*b4+1] = fmaf(wv[kk], x4.y, acc[4*b4+1]);
                acc[4*b4+2] = fmaf(wv[kk], x4.z, acc[4*b4+2]);
                acc[4*b4+3] = fmaf(wv[kk], x4.w, acc[4*b4+3]);
            }
        }
    }
    for (int b = 0; b < 64; ++b)
        Yq[(tq*64 + b)*512 + j] = acc[b];
}

// ---------- pre-BiLSTM recurrence (h discarded; c masked; h = tanh(c)) ----------
__global__ __launch_bounds__(384)
void rec_pre_kernel(const float* __restrict__ Xp, const float* __restrict__ Xq,
                    const u32* __restrict__ Whh,
                    const float* __restrict__ mask_p, const float* __restrict__ mask_q,
                    float* __restrict__ Hp, float* __restrict__ Hq)
{
    int bid = blockIdx.x;
    int sub = bid & 127; int b = sub >> 1; int dir = sub & 1;
    const float* X; const float* mask; float* Hout; int T;
    if (bid < 128) { X = Xp; mask = mask_p; Hout = Hp; T = TP; }
    else           { X = Xq; mask = mask_q; Hout = Hq; T = TQ; }
    int j = threadIdx.x;
    __shared__ __align__(16) _Float16 h16[128];
    __shared__ float gates[384];
    u32 w[64];
    #pragma unroll
    for (int q = 0; q < 64; ++q) w[q] = Whh[q*512 + j];
    if (j < 128) h16[j] = (_Float16)0.f;
    float c = 0.f;
    int ti0 = dir ? (T-1) : 0;
    float x_c = X[(ti0*64 + b)*512 + j];
    float m_c = mask[ti0*64 + b];
    int cls = j >> 7;                            // 0:i 1:f 2:g (wave-uniform)
    __syncthreads();
    const u32* h32 = (const u32*)h16;
    for (int s = 0; s < T; ++s) {
        int ti = dir ? (T-1-s) : s;
        int s1 = (s+1 < T) ? (s+1) : s;
        int tn = dir ? (T-1-s1) : s1;
        float x_n = X[(tn*64 + b)*512 + j];
        float m_n = mask[tn*64 + b];
        // cooperative h read: lane l holds pair l; broadcast via readlane
        u32 hp = h32[j & 63];
        float a0 = x_c, a1 = 0.f, a2 = 0.f, a3 = 0.f;
        #pragma unroll
        for (int q = 0; q < 64; q += 4) {
            u32 h0 = lane_bcast(hp, q),   h1 = lane_bcast(hp, q+1);
            u32 h2v = lane_bcast(hp, q+2), h3 = lane_bcast(hp, q+3);
            a0 = dot2f(w[q],   h0,  a0);
            a1 = dot2f(w[q+1], h1,  a1);
            a2 = dot2f(w[q+2], h2v, a2);
            a3 = dot2f(w[q+3], h3,  a3);
        }
        float g = (a0 + a1) + (a2 + a3);
        gates[j] = (cls == 2) ? tanh_fast(g) : sigm_fast(g);
        __syncthreads();
        if (j < 128) {
            float gi = gates[j], gf = gates[128+j], gg = gates[256+j];
            c = gf*c + gi*gg;
            c *= m_c;
            float h = tanh_fast(c);
            h16[j] = (_Float16)h;
            Hout[(ti*64 + b)*256 + dir*128 + j] = h;
        }
        __syncthreads();
        x_c = x_n; m_c = m_n;
    }
}

// ---------- Match-LSTM recurrence: one block per (b, dir) ----------
// amdgpu_waves_per_eu(2,2): grid 128 = 1 block/CU, LDS now ~3 KB; grant the
// full 256-reg budget so whh[64]+wh[64]+Yqr[32]+aqr[16]+wa[16] stay resident.
__global__ __launch_bounds__(512)
__attribute__((amdgpu_waves_per_eu(2, 2)))
void match_kernel(const float* __restrict__ ap,   // [600][64][256]
                  const float* __restrict__ aqg,  // [60][64][256]
                  const float* __restrict__ Zp,   // [600][64][512]
                  const float* __restrict__ Yq,   // [60][64][512]
                  const float* __restrict__ Wa,   // [256]
                  const float* __restrict__ mask_p,
                  const u32* __restrict__ PMwh,   // [64][256] packed Wh
                  const u32* __restrict__ PMhh,   // [64][512] packed Whh
                  float* __restrict__ out)        // [600][64][256]
{
    int bid = blockIdx.x; int b = bid >> 1; int dir = bid & 1;
    int tid = threadIdx.x;
    __shared__ __align__(16) u32 sumt16[160];        // [sb][20]: pairs [16sb..16sb+16)
    __shared__ float gates[512];
    __shared__ __align__(16) _Float16 h16[128];
    __shared__ __align__(16) _Float16 e16[64];

    int tq = tid >> 3, sb = tid & 7;

    // ---- step-invariant register staging ----
    u32 aqr[16];                                     // aq[tq][32sb..32sb+32) fp16 pairs
    if (tq < 60) {
        #pragma unroll
        for (int i = 0; i < 16; ++i) {
            float2 a = *(const float2*)&aqg[(tq*64 + b)*256 + 32*sb + 2*i];
            aqr[i] = pack2(a.x, a.y);
        }
    } else {
        #pragma unroll
        for (int i = 0; i < 16; ++i) aqr[i] = 0u;
    }
    u32 wa_reg[16];                                  // wa pairs [16sb..16sb+16)
    #pragma unroll
    for (int i = 0; i < 16; ++i) {
        float2 w2 = *(const float2*)&Wa[32*sb + 2*i];
        wa_reg[i] = pack2(w2.x, w2.y);
    }
    u32 Yqr[32];                                     // Yqr[r] = pack2(Yq[2r][tid], Yq[2r+1][tid])
    #pragma unroll
    for (int r = 0; r < 30; ++r) {
        float y0 = Yq[((2*r  )*64 + b)*512 + tid];
        float y1 = Yq[((2*r+1)*64 + b)*512 + tid];
        Yqr[r] = pack2(y0, y1);
    }
    Yqr[30] = 0u; Yqr[31] = 0u;
    u32 whh[64];
    #pragma unroll
    for (int q = 0; q < 64; ++q) whh[q] = PMhh[q*512 + tid];
    u32 wh[64];
    {
        int jw = tid & 255;
        #pragma unroll
        for (int q = 0; q < 64; ++q) wh[q] = PMwh[q*256 + jw];
    }
    if (tid < 128) h16[tid] = (_Float16)0.f;

    float c = 0.f;
    int ti0 = dir ? (TP-1) : 0;
    float zp_c = Zp[(ti0*64 + b)*512 + tid];
    float ap_c = (tid < 256) ? ap[(ti0*64 + b)*256 + tid] : 0.f;
    float m_c  = mask_p[ti0*64 + b];
    int cls = tid >> 7;                               // gate class, wave-uniform
    const u32 ONE2 = 0x3C003C00u;                     // fp16 (1.0, 1.0)
    float h_out = 0.f; int ti_prev = 0;
    __syncthreads();

    const u32* h32 = (const u32*)h16;
    const u32* e32 = (const u32*)e16;

    for (int s = 0; s < TP; ++s) {
        int ti = dir ? (TP-1-s) : s;
        int s1 = (s+1 < TP) ? (s+1) : s;
        int tn = dir ? (TP-1-s1) : s1;

        // deferred out-store from previous step + prefetches: their vmcnt drain
        // at bar1 is covered by P1's compute
        if (s && tid < 128)
            out[(ti_prev*64 + b)*256 + dir*128 + tid] = h_out;
        float zp_n = Zp[(tn*64 + b)*512 + tid];
        float ap_n = (tid < 256) ? ap[(tn*64 + b)*256 + tid] : 0.f;
        float m_n  = mask_p[tn*64 + b];

        // ---- P1: hwhh (reg) + sumt = ap + h@Wh.T (tid<256) ----
        u32 hp = h32[tid & 63];                       // coop read: lane l holds pair l
        float w0 = 0.f, w1 = 0.f, w2a = 0.f, w3a = 0.f;
        if (tid < 256) {
            float s0 = ap_c, s1a = 0.f, s2 = 0.f, s3 = 0.f;
            #pragma unroll
            for (int q = 0; q < 64; q += 4) {
                u32 h0 = lane_bcast(hp, q),   u1 = lane_bcast(hp, q+1);
                u32 h2v = lane_bcast(hp, q+2), h3 = lane_bcast(hp, q+3);
                w0  = dot2f(whh[q],   h0,  w0);  s0  = dot2f(wh[q],   h0,  s0);
                w1  = dot2f(whh[q+1], u1,  w1);  s1a = dot2f(wh[q+1], u1,  s1a);
                w2a = dot2f(whh[q+2], h2v, w2a); s2  = dot2f(wh[q+2], h2v, s2);
                w3a = dot2f(whh[q+3], h3,  w3a); s3  = dot2f(wh[q+3], h3,  s3);
            }
            float st = (s0 + s1a) + (s2 + s3);
            float so = __shfl_xor(st, 1);
            if ((tid & 1) == 0) {
                int p = tid >> 1;
                sumt16[(p >> 4)*20 + (p & 15)] = pack2(st, so);
            }
        } else {
            #pragma unroll
            for (int q = 0; q < 64; q += 4) {
                u32 h0 = lane_bcast(hp, q),   u1 = lane_bcast(hp, q+1);
                u32 h2v = lane_bcast(hp, q+2), h3 = lane_bcast(hp, q+3);
                w0  = dot2f(whh[q],   h0,  w0);
                w1  = dot2f(whh[q+1], u1,  w1);
                w2a = dot2f(whh[q+2], h2v, w2a);
                w3a = dot2f(whh[q+3], h3,  w3a);
            }
        }
        float hwhh = (w0 + w1) + (w2a + w3a);
        __syncthreads();                              // bar1

        // ---- P2: scores -> e16; only sumt comes from LDS now ----
        {
            const uint4* sv4 = (const uint4*)&sumt16[sb*20];
            uint4 sv0 = sv4[0], sv1 = sv4[1], sv2 = sv4[2], sv3 = sv4[3];
            u32 sa[16] = {sv0.x,sv0.y,sv0.z,sv0.w, sv1.x,sv1.y,sv1.z,sv1.w,
                          sv2.x,sv2.y,sv2.z,sv2.w, sv3.x,sv3.y,sv3.z,sv3.w};
            float p0 = 0.f, p1 = 0.f, p2 = 0.f, p3 = 0.f;
            #pragma unroll
            for (int i = 0; i < 16; ++i) {
                f16x2 sm = __builtin_bit_cast(f16x2, aqr[i]) +
                           __builtin_bit_cast(f16x2, sa[i]);      // v_pk_add_f16
                f16x2 wv = __builtin_bit_cast(f16x2, wa_reg[i]);
                float t0 = tanh_fast((float)sm.x);
                float t1 = tanh_fast((float)sm.y);
                if (i & 1) { p2 = fmaf((float)wv.x, t0, p2); p3 = fmaf((float)wv.y, t1, p3); }
                else       { p0 = fmaf((float)wv.x, t0, p0); p1 = fmaf((float)wv.y, t1, p1); }
            }
            float part = (p0 + p1) + (p2 + p3);
            part += __shfl_xor(part, 1);
            part += __shfl_xor(part, 2);
            part += __shfl_xor(part, 4);
            float sc = fminf(9.f, fmaxf(-9.f, part));
            float e = exp2_fast(sc * 1.44269504f);
            if (tq >= 60) e = 0.f;
            if (sb == 0) e16[tq] = (_Float16)e;
        }
        __syncthreads();                              // bar2

        // ---- P4: gates = Zp + rn*(sum_tq e*Yq) + hwhh ; Yq from registers ----
        {
            u32 ep = e32[tid & 31];                   // coop read: lane l holds e-pair l
            float y0 = 0.f, y1 = 0.f, S0 = 0.f, S1 = 0.f;
            #pragma unroll
            for (int r4 = 0; r4 < 8; ++r4) {
                u32 e0 = lane_bcast(ep, 4*r4+0), e1 = lane_bcast(ep, 4*r4+1);
                u32 e2 = lane_bcast(ep, 4*r4+2), e3 = lane_bcast(ep, 4*r4+3);
                y0 = dot2f(Yqr[4*r4+0], e0, y0); S0 = dot2f(ONE2, e0, S0);
                y1 = dot2f(Yqr[4*r4+1], e1, y1); S1 = dot2f(ONE2, e1, S1);
                y0 = dot2f(Yqr[4*r4+2], e2, y0); S0 = dot2f(ONE2, e2, S0);
                y1 = dot2f(Yqr[4*r4+3], e3, y1); S1 = dot2f(ONE2, e3, S1);
            }
            float rn = rcp_fast(S0 + S1);
            float g = zp_c + rn * (y0 + y1) + hwhh;
            gates[tid] = (cls == 2) ? tanh_fast(g) : sigm_fast(g);
        }
        __syncthreads();                              // bar3

        // ---- P5: cell; h,c masked after cell; out-store deferred to next top ----
        if (tid < 128) {
            float gi = gates[tid], gf = gates[128+tid], gg = gates[256+tid], go = gates[384+tid];
            c = gf*c + gi*gg;
            float h = go * tanh_fast(c);
            h *= m_c; c *= m_c;
            h16[tid] = (_Float16)h;
            h_out = h; ti_prev = ti;
        }
        __syncthreads();                              // bar4 (h ready)
        zp_c = zp_n; ap_c = ap_n; m_c = m_n;
    }
    if (tid < 128)
        out[(ti_prev*64 + b)*256 + dir*128 + tid] = h_out;
}

// ---------- workspace layout (floats) ----------
#define O_BUFX   0UL          // 19,660,800  Xp0 -> Xp1 -> Zp
#define O_BUFXQ  19660800UL   //  1,966,080  Xq0 -> Xq1 -> Yq
#define O_HP0    21626880UL   //  9,830,400  Hp0 -> ap
#define O_HQ0    31457280UL   //    983,040  Hq0 -> aq
#define O_HP1    32440320UL   //  9,830,400
#define O_HQ1    42270720UL   //    983,040
#define O_WT0    43253760UL   //    176,128
#define O_WT1    43429888UL   //    131,072
#define O_WTQ    43560960UL   //     65,536
#define O_WTP    43626496UL   //     65,536
#define O_WTZ    43692032UL   //    131,072
#define O_P0HH   43823104UL   //     32,768 u32
#define O_P1HH   43855872UL
#define O_PMHH   43888640UL
#define O_PMWH   43921408UL   //     16,384 u32

extern "C" void kernel_launch(void* const* d_in, const int* in_sizes, int n_in,
                              void* d_out, int out_size, void* d_ws, size_t ws_size,
                              hipStream_t stream)
{
    const float* passage  = (const float*)d_in[0];
    const float* question = (const float*)d_in[1];
    const float* mask_p   = (const float*)d_in[2];
    const float* mask_q   = (const float*)d_in[3];
    const float* pre0_Wih = (const float*)d_in[4];
    const float* pre0_Whh = (const float*)d_in[5];
    const float* pre0_b   = (const float*)d_in[6];
    const float* pre1_Wih = (const float*)d_in[7];
    const float* pre1_Whh = (const float*)d_in[8];
    const float* pre1_b   = (const float*)d_in[9];
    const float* mq_Wq    = (const float*)d_in[10];
    const float* mq_Wp    = (const float*)d_in[11];
    const float* mq_bp    = (const float*)d_in[12];
    const float* mq_Wh    = (const float*)d_in[13];
    const float* mq_Wa    = (const float*)d_in[14];
    // d_in[15] = mq_ba: softmax-invariant, skipped
    const float* mq_Wih   = (const float*)d_in[16];
    const float* mq_Whh   = (const float*)d_in[17];
    const float* mq_b     = (const float*)d_in[18];

    float* ws = (float*)d_ws;
    float* bufX  = ws + O_BUFX;
    float* bufXq = ws + O_BUFXQ;
    float* Hp0   = ws + O_HP0;
    float* Hq0   = ws + O_HQ0;
    float* Hp1   = ws + O_HP1;
    float* Hq1   = ws + O_HQ1;
    float* WT0   = ws + O_WT0;
    float* WT1   = ws + O_WT1;
    float* WTq   = ws + O_WTQ;
    float* WTp   = ws + O_WTP;
    float* WTz   = ws + O_WTZ;
    u32*   P0hh  = (u32*)(ws + O_P0HH);
    u32*   P1hh  = (u32*)(ws + O_P1HH);
    u32*   PMhh  = (u32*)(ws + O_PMHH);
    u32*   PMwh  = (u32*)(ws + O_PMWH);
    float* ap = Hp0;   // Hp0 dead after proj1
    float* aq = Hq0;
    float* Zp = bufX;  // Xp1 dead after rec1
    float* Yq = bufXq; // Xq1 dead after rec1

    prep_kernel<<<688, 256, 0, stream>>>(pre0_Wih, pre0_Whh, pre1_Wih, pre1_Whh,
                                         mq_Wq, mq_Wp, mq_Wh, mq_Whh,
                                         WT0, WT1, WTq, WTp, WTz, mq_Wih,
                                         P0hh, P1hh, PMhh, PMwh);
    proj_kernel<EMB, 512><<<660, 512, 0, stream>>>(passage, WT0, pre0_b, bufX, TP,
                                                   question, WT0, pre0_b, bufXq);
    rec_pre_kernel<<<256, 384, 0, stream>>>(bufX, bufXq, P0hh, mask_p, mask_q, Hp0, Hq0);
    proj_kernel<256, 512><<<660, 512, 0, stream>>>(Hp0, WT1, pre1_b, bufX, TP,
                                                   Hq0, WT1, pre1_b, bufXq);
    rec_pre_kernel<<<256, 384, 0, stream>>>(bufX, bufXq, P1hh, mask_p, mask_q, Hp1, Hq1);
    proj_kernel<256, 256><<<660, 256, 0, stream>>>(Hp1, WTp, mq_bp, ap, TP,
                                                   Hq1, WTq, nullptr, aq);
    proj_kernel<256, 512><<<600, 512, 0, stream>>>(Hp1, WTz, mq_b, Zp, TP,
                                                   nullptr, nullptr, nullptr, nullptr);
    yq_kernel<<<60, 512, 0, stream>>>(Hq1, mq_Wih, Yq);
    match_kernel<<<128, 512, 0, stream>>>(ap, aq, Zp, Yq, mq_Wa, mask_p,
                                          PMwh, PMhh, (float*)d_out);
}